// Round 1
// baseline (2488.028 us; speedup 1.0000x reference)
//
#include <hip/hip_runtime.h>
#include <cstdint>
#include <cstddef>

// ---------------- problem constants ----------------
#define NN 30000        // nodes
#define NE 400000       // edges per scatter set / GAT graph (pre-self-loop)
#define EG (NE + NN)    // GAT edges incl self loops
#define FIN 512
#define NH 128
#define NHEAD 4
#define NCLS 10
#define NSETS 5
#define BN_EPS 1e-5f

// ---------------- workspace layout (bytes) ----------------
constexpr size_t alg(size_t x) { return (x + 255) & ~size_t(255); }
constexpr size_t SZ_N128 = (size_t)NN * 128 * 4;   // 15,360,000
constexpr size_t SZ_N512 = (size_t)NN * 512 * 4;   // 61,440,000
constexpr size_t OFF_H     = 0;
constexpr size_t OFF_X2    = OFF_H    + alg(SZ_N128);
constexpr size_t OFF_HH    = OFF_X2   + alg(SZ_N128);
constexpr size_t OFF_GOUT  = OFF_HH   + alg(SZ_N512);  // tmp = gout[0:N*128], xcur = gout[N*128:2N*128]
constexpr size_t OFF_AS    = OFF_GOUT + alg(SZ_N512);
constexpr size_t OFF_AD    = OFF_AS   + alg((size_t)NN * 4 * 4);
constexpr size_t OFF_MM    = OFF_AD   + alg((size_t)NN * 4 * 4);
constexpr size_t OFF_DD    = OFF_MM   + alg((size_t)NN * 4 * 4);
constexpr size_t OFF_SPOFF = OFF_DD   + alg((size_t)NN * 4 * 4);
constexpr size_t OFF_SPSRC = OFF_SPOFF + alg((size_t)NSETS * (NN + 1) * 4);
constexpr size_t OFF_SPW   = OFF_SPSRC + alg((size_t)NSETS * NE * 4);
constexpr size_t OFF_GOFF  = OFF_SPW   + alg((size_t)NSETS * NE * 4);
constexpr size_t OFF_GSRC  = OFF_GOFF  + alg((size_t)(NN + 1) * 4);
constexpr size_t OFF_CNT   = OFF_GSRC  + alg((size_t)EG * 4);
constexpr size_t WS_NEED   = OFF_CNT   + alg((size_t)NN * 4);   // ~174 MB

// ---------------- small helpers ----------------
__device__ __forceinline__ float lrelu02(float v) { return v > 0.f ? v : 0.2f * v; }
__device__ __forceinline__ float eluf(float v)    { return v > 0.f ? v : __expf(v) - 1.f; }

// ---------------- CSR build ----------------
__global__ void count_dst(const int* __restrict__ dst, int n, int* __restrict__ cnt) {
    for (int i = blockIdx.x * blockDim.x + threadIdx.x; i < n; i += gridDim.x * blockDim.x)
        atomicAdd(&cnt[dst[i]], 1);
}

__global__ void count_gat(const int* __restrict__ ei, int* __restrict__ cnt) {
    for (int i = blockIdx.x * blockDim.x + threadIdx.x; i < EG; i += gridDim.x * blockDim.x) {
        int d = (i < NE) ? ei[NE + i] : (i - NE);
        atomicAdd(&cnt[d], 1);
    }
}

// exclusive scan over NN counts (single block, 1024 threads)
__global__ void exscan30k(const int* __restrict__ cnt, int* __restrict__ off) {
    constexpr int n = NN;
    constexpr int per = 30;               // 1024*30 = 30720 >= 30000
    __shared__ int s[1024];
    const int t = threadIdx.x;
    const int base0 = t * per;
    int sum = 0;
    #pragma unroll
    for (int i = 0; i < per; ++i) {
        int idx = base0 + i;
        sum += (idx < n) ? cnt[idx] : 0;
    }
    s[t] = sum;
    __syncthreads();
    for (int d = 1; d < 1024; d <<= 1) {
        int v = (t >= d) ? s[t - d] : 0;
        __syncthreads();
        s[t] += v;
        __syncthreads();
    }
    int run = s[t] - sum;                 // exclusive prefix of this thread's chunk
    #pragma unroll
    for (int i = 0; i < per; ++i) {
        int idx = base0 + i;
        if (idx < n) { off[idx] = run; run += cnt[idx]; }
    }
    if (t == 1023) off[n] = s[1023];
}

__global__ void fill_sp(const int* __restrict__ si, const float* __restrict__ w,
                        const int* __restrict__ off, int* __restrict__ cur,
                        int* __restrict__ osrc, float* __restrict__ ow) {
    for (int i = blockIdx.x * blockDim.x + threadIdx.x; i < NE; i += gridDim.x * blockDim.x) {
        int d = si[NE + i];
        int p = off[d] + atomicAdd(&cur[d], 1);
        osrc[p] = si[i];
        ow[p]   = w[i];
    }
}

__global__ void fill_gat(const int* __restrict__ ei, const int* __restrict__ off,
                         int* __restrict__ cur, int* __restrict__ gsrc) {
    for (int i = blockIdx.x * blockDim.x + threadIdx.x; i < EG; i += gridDim.x * blockDim.x) {
        int sidx, d;
        if (i < NE) { sidx = ei[i]; d = ei[NE + i]; }
        else        { sidx = i - NE; d = i - NE; }
        int p = off[d] + atomicAdd(&cur[d], 1);
        gsrc[p] = sidx;
    }
}

// ---------------- segment gather-sum (solo_pass): out[n] = sum_j w[j]*in[src[j]] ----------------
template<int DO_ABS>
__global__ void __launch_bounds__(256) sp_gather(const int* __restrict__ off, const int* __restrict__ src,
                                                 const float* __restrict__ w, const float* __restrict__ in,
                                                 float* __restrict__ out) {
    const int wid  = blockIdx.x * 4 + (threadIdx.x >> 6);   // one wave per node; 7500*4 == 30000 exactly
    const int lane = threadIdx.x & 63;
    const int s0 = off[wid], s1 = off[wid + 1];
    float2 acc = {0.f, 0.f};
    for (int j = s0; j < s1; ++j) {
        const int sidx = src[j];
        const float wj = w[j];
        float2 v = *(const float2*)(in + (size_t)sidx * 128 + lane * 2);
        acc.x += wj * v.x;
        acc.y += wj * v.y;
    }
    if (DO_ABS) { acc.x = fabsf(acc.x); acc.y = fabsf(acc.y); }
    *(float2*)(out + (size_t)wid * 128 + lane * 2) = acc;
}

// ---------------- tiled fp32 GEMM, 64x64 tile, BK=32, 256 thr, 4x4/thread ----------------
#define GM_LIN 0    // C = A@B + bias ; store C and C2 (dup)
#define GM_PLAIN 1  // C = A@B
#define GM_MLP 2    // C2 += BN( elu(A)@B + bias )

template<int K, int NC, int MODE>
__global__ void __launch_bounds__(256) gemm64(const float* __restrict__ A, const float* __restrict__ B,
                                              const float* __restrict__ bias,
                                              float* __restrict__ C, float* __restrict__ C2,
                                              const float* __restrict__ bng, const float* __restrict__ bnb,
                                              const float* __restrict__ bnm, const float* __restrict__ bnv,
                                              int M) {
    __shared__ float As[32][68];   // transposed A-tile: As[k][m]
    __shared__ float Bs[32][68];
    const int bm = blockIdx.x * 64;
    const int bn = blockIdx.y * 64;
    const int t  = threadIdx.x;
    const int tr = (t >> 4) << 2;
    const int tc = (t & 15) << 2;
    float acc[4][4] = {};

    for (int k0 = 0; k0 < K; k0 += 32) {
        #pragma unroll
        for (int i = 0; i < 2; ++i) {
            int v = t + i * 256;
            int r = v >> 3, cg = (v & 7) << 2;
            int row = bm + r;
            float4 val = make_float4(0.f, 0.f, 0.f, 0.f);
            if (row < M) val = *(const float4*)(A + (size_t)row * K + k0 + cg);
            if (MODE == GM_MLP) {
                val.x = eluf(val.x); val.y = eluf(val.y); val.z = eluf(val.z); val.w = eluf(val.w);
            }
            As[cg + 0][r] = val.x; As[cg + 1][r] = val.y; As[cg + 2][r] = val.z; As[cg + 3][r] = val.w;
        }
        #pragma unroll
        for (int i = 0; i < 2; ++i) {
            int v = t + i * 256;
            int r = v >> 4, cg = (v & 15) << 2;
            *(float4*)&Bs[r][cg] = *(const float4*)(B + (size_t)(k0 + r) * NC + bn + cg);
        }
        __syncthreads();
        #pragma unroll
        for (int k = 0; k < 32; ++k) {
            float4 a = *(const float4*)&As[k][tr];
            float4 b = *(const float4*)&Bs[k][tc];
            #pragma unroll
            for (int ii = 0; ii < 4; ++ii) {
                float av = (&a.x)[ii];
                #pragma unroll
                for (int jj = 0; jj < 4; ++jj)
                    acc[ii][jj] = fmaf(av, (&b.x)[jj], acc[ii][jj]);
            }
        }
        __syncthreads();
    }

    const int col0 = bn + tc;
    #pragma unroll
    for (int i = 0; i < 4; ++i) {
        int row = bm + tr + i;
        if (row < M) {
            if (MODE == GM_LIN) {
                float4 v;
                v.x = acc[i][0] + bias[col0 + 0];
                v.y = acc[i][1] + bias[col0 + 1];
                v.z = acc[i][2] + bias[col0 + 2];
                v.w = acc[i][3] + bias[col0 + 3];
                *(float4*)(C  + (size_t)row * NC + col0) = v;
                *(float4*)(C2 + (size_t)row * NC + col0) = v;
            } else if (MODE == GM_PLAIN) {
                float4 v = {acc[i][0], acc[i][1], acc[i][2], acc[i][3]};
                *(float4*)(C + (size_t)row * NC + col0) = v;
            } else { // GM_MLP: BN + accumulate into C2
                float4 old = *(const float4*)(C2 + (size_t)row * NC + col0);
                #pragma unroll
                for (int jj = 0; jj < 4; ++jj) {
                    float sc = bng[col0 + jj] * rsqrtf(bnv[col0 + jj] + BN_EPS);
                    float sh = bnb[col0 + jj] - bnm[col0 + jj] * sc;
                    float z  = acc[i][jj] + bias[col0 + jj];
                    (&old.x)[jj] += z * sc + sh;
                }
                *(float4*)(C2 + (size_t)row * NC + col0) = old;
            }
        }
    }
}

// ---------------- GAT attention scores: a_s[n,h], a_d[n,h] ----------------
__global__ void __launch_bounds__(256) att_scores(const float* __restrict__ hh,
                                                  const float* __restrict__ att_s, const float* __restrict__ att_d,
                                                  float* __restrict__ as_, float* __restrict__ ad_) {
    __shared__ float ss[512], sd[512];
    for (int i = threadIdx.x; i < 512; i += 256) { ss[i] = att_s[i]; sd[i] = att_d[i]; }
    __syncthreads();
    const int wid  = blockIdx.x * 4 + (threadIdx.x >> 6);
    const int lane = threadIdx.x & 63;
    const float* row = hh + (size_t)wid * 512 + lane * 8;
    float4 v0 = *(const float4*)row;
    float4 v1 = *(const float4*)(row + 4);
    float4 s0 = *(const float4*)(ss + lane * 8), s1 = *(const float4*)(ss + lane * 8 + 4);
    float4 d0 = *(const float4*)(sd + lane * 8), d1 = *(const float4*)(sd + lane * 8 + 4);
    float ps = v0.x*s0.x + v0.y*s0.y + v0.z*s0.z + v0.w*s0.w
             + v1.x*s1.x + v1.y*s1.y + v1.z*s1.z + v1.w*s1.w;
    float pd = v0.x*d0.x + v0.y*d0.y + v0.z*d0.z + v0.w*d0.w
             + v1.x*d1.x + v1.y*d1.y + v1.z*d1.z + v1.w*d1.w;
    #pragma unroll
    for (int d = 1; d < 16; d <<= 1) { ps += __shfl_xor(ps, d); pd += __shfl_xor(pd, d); }
    if ((lane & 15) == 0) {
        const int hd = lane >> 4;
        as_[(size_t)wid * 4 + hd] = ps;
        ad_[(size_t)wid * 4 + hd] = pd;
    }
}

// ---------------- per-dst segment max + exp-sum (thread per node) ----------------
__global__ void att_mden(const int* __restrict__ goff, const int* __restrict__ gsrc,
                         const float* __restrict__ as_, const float* __restrict__ ad_,
                         float* __restrict__ mmax, float* __restrict__ dden) {
    const int n = blockIdx.x * 256 + threadIdx.x;
    if (n >= NN) return;
    const int s0 = goff[n], s1 = goff[n + 1];
    float4 adv = *(const float4*)(ad_ + (size_t)n * 4);
    float m0 = -1e30f, m1 = -1e30f, m2 = -1e30f, m3 = -1e30f;
    for (int j = s0; j < s1; ++j) {
        int s = gsrc[j];
        float4 av = *(const float4*)(as_ + (size_t)s * 4);
        m0 = fmaxf(m0, lrelu02(av.x + adv.x));
        m1 = fmaxf(m1, lrelu02(av.y + adv.y));
        m2 = fmaxf(m2, lrelu02(av.z + adv.z));
        m3 = fmaxf(m3, lrelu02(av.w + adv.w));
    }
    float d0 = 0.f, d1 = 0.f, d2 = 0.f, d3 = 0.f;
    for (int j = s0; j < s1; ++j) {
        int s = gsrc[j];
        float4 av = *(const float4*)(as_ + (size_t)s * 4);
        d0 += __expf(lrelu02(av.x + adv.x) - m0);
        d1 += __expf(lrelu02(av.y + adv.y) - m1);
        d2 += __expf(lrelu02(av.z + adv.z) - m2);
        d3 += __expf(lrelu02(av.w + adv.w) - m3);
    }
    *(float4*)(mmax + (size_t)n * 4) = make_float4(m0, m1, m2, m3);
    *(float4*)(dden + (size_t)n * 4) = make_float4(d0, d1, d2, d3);
}

// ---------------- GAT aggregation: gout[n] = sum_j alpha_j * hh[src_j] + gat_b ----------------
__global__ void __launch_bounds__(256) gat_agg(const int* __restrict__ goff, const int* __restrict__ gsrc,
                                               const float* __restrict__ as_, const float* __restrict__ ad_,
                                               const float* __restrict__ mmax, const float* __restrict__ dden,
                                               const float* __restrict__ hh, const float* __restrict__ gat_b,
                                               float* __restrict__ gout) {
    const int wid  = blockIdx.x * 4 + (threadIdx.x >> 6);
    const int lane = threadIdx.x & 63;
    const int hd   = lane >> 4;                 // head owning channels lane*8..lane*8+7
    const float adv = ad_[(size_t)wid * 4 + hd];
    const float mv  = mmax[(size_t)wid * 4 + hd];
    const float inv = 1.f / (dden[(size_t)wid * 4 + hd] + 1e-16f);
    const int s0 = goff[wid], s1 = goff[wid + 1];
    float4 a0 = {0,0,0,0}, a1 = {0,0,0,0};
    for (int j = s0; j < s1; ++j) {
        const int s = gsrc[j];
        float e = lrelu02(as_[(size_t)s * 4 + hd] + adv);
        float alpha = __expf(e - mv) * inv;
        const float* row = hh + (size_t)s * 512 + lane * 8;
        float4 v0 = *(const float4*)row;
        float4 v1 = *(const float4*)(row + 4);
        a0.x = fmaf(alpha, v0.x, a0.x); a0.y = fmaf(alpha, v0.y, a0.y);
        a0.z = fmaf(alpha, v0.z, a0.z); a0.w = fmaf(alpha, v0.w, a0.w);
        a1.x = fmaf(alpha, v1.x, a1.x); a1.y = fmaf(alpha, v1.y, a1.y);
        a1.z = fmaf(alpha, v1.z, a1.z); a1.w = fmaf(alpha, v1.w, a1.w);
    }
    const float4 b0 = *(const float4*)(gat_b + lane * 8);
    const float4 b1 = *(const float4*)(gat_b + lane * 8 + 4);
    a0.x += b0.x; a0.y += b0.y; a0.z += b0.z; a0.w += b0.w;
    a1.x += b1.x; a1.y += b1.y; a1.z += b1.z; a1.w += b1.w;
    float* orow = gout + (size_t)wid * 512 + lane * 8;
    *(float4*)orow = a0;
    *(float4*)(orow + 4) = a1;
}

// ---------------- final: out = log_softmax( elu(bn0(x2)) @ outW + outb ) ----------------
__global__ void __launch_bounds__(256) final_out(const float* __restrict__ x2,
                                                 const float* __restrict__ bn0g, const float* __restrict__ bn0b,
                                                 const float* __restrict__ bn0m, const float* __restrict__ bn0v,
                                                 const float* __restrict__ outW, const float* __restrict__ outb,
                                                 float* __restrict__ out) {
    __shared__ float sW[128 * 12];   // padded [128][12]
    __shared__ float sSc[128], sSh[128];
    for (int i = threadIdx.x; i < 1280; i += 256) {
        int r = i / 10, c = i - r * 10;
        sW[r * 12 + c] = outW[i];
    }
    if (threadIdx.x < 128) {
        int c = threadIdx.x;
        float sc = bn0g[c] * rsqrtf(bn0v[c] + BN_EPS);
        sSc[c] = sc;
        sSh[c] = bn0b[c] - bn0m[c] * sc;
    }
    __syncthreads();
    const int wid  = blockIdx.x * 4 + (threadIdx.x >> 6);
    const int lane = threadIdx.x & 63;
    const int c0 = lane * 2;
    float2 a = *(const float2*)(x2 + (size_t)wid * 128 + c0);
    float a0 = eluf(a.x * sSc[c0] + sSh[c0]);
    float a1 = eluf(a.y * sSc[c0 + 1] + sSh[c0 + 1]);
    float p[NCLS];
    #pragma unroll
    for (int j = 0; j < NCLS; ++j)
        p[j] = a0 * sW[c0 * 12 + j] + a1 * sW[(c0 + 1) * 12 + j];
    #pragma unroll
    for (int j = 0; j < NCLS; ++j) {
        float v = p[j];
        v += __shfl_xor(v, 1);  v += __shfl_xor(v, 2);  v += __shfl_xor(v, 4);
        v += __shfl_xor(v, 8);  v += __shfl_xor(v, 16); v += __shfl_xor(v, 32);
        p[j] = v;
    }
    float z[NCLS];
    #pragma unroll
    for (int j = 0; j < NCLS; ++j) z[j] = p[j] + outb[j];
    float m = z[0];
    #pragma unroll
    for (int j = 1; j < NCLS; ++j) m = fmaxf(m, z[j]);
    float ssum = 0.f;
    #pragma unroll
    for (int j = 0; j < NCLS; ++j) ssum += __expf(z[j] - m);
    float lse = m + __logf(ssum);
    #pragma unroll
    for (int j = 0; j < NCLS; ++j)
        if (lane == j) out[(size_t)wid * NCLS + j] = z[j] - lse;
}

// ---------------- launcher ----------------
extern "C" void kernel_launch(void* const* d_in, const int* in_sizes, int n_in,
                              void* d_out, int out_size, void* d_ws, size_t ws_size,
                              hipStream_t stream) {
    const float* x         = (const float*)d_in[0];
    const int*   edge_ix   = (const int*)  d_in[1];
    const int*   scat_idx  = (const int*)  d_in[2];
    const float* scat_w    = (const float*)d_in[3];
    const float* lin_W     = (const float*)d_in[4];
    const float* lin_b     = (const float*)d_in[5];
    const float* gat_W     = (const float*)d_in[6];
    const float* att_src   = (const float*)d_in[7];
    const float* att_dst   = (const float*)d_in[8];
    const float* gat_b     = (const float*)d_in[9];
    const float* mlp_W     = (const float*)d_in[10];
    const float* mlp_b     = (const float*)d_in[11];
    const float* bn_g      = (const float*)d_in[12];
    const float* bn_b      = (const float*)d_in[13];
    const float* bn_m      = (const float*)d_in[14];
    const float* bn_v      = (const float*)d_in[15];
    const float* bn0_g     = (const float*)d_in[16];
    const float* bn0_b     = (const float*)d_in[17];
    const float* bn0_m     = (const float*)d_in[18];
    const float* bn0_v     = (const float*)d_in[19];
    const float* out_W     = (const float*)d_in[20];
    const float* out_b     = (const float*)d_in[21];
    float* out = (float*)d_out;

    char* ws = (char*)d_ws;
    float* h      = (float*)(ws + OFF_H);
    float* x2     = (float*)(ws + OFF_X2);
    float* hh     = (float*)(ws + OFF_HH);
    float* gout   = (float*)(ws + OFF_GOUT);
    float* tmp    = gout;                              // aliases gout[0 : N*128]
    float* xcur   = gout + (size_t)NN * 128;           // aliases gout[N*128 : 2*N*128]
    float* asrc   = (float*)(ws + OFF_AS);
    float* adst   = (float*)(ws + OFF_AD);
    float* mmax   = (float*)(ws + OFF_MM);
    float* dden   = (float*)(ws + OFF_DD);
    int*   sp_off = (int*)(ws + OFF_SPOFF);
    int*   sp_src = (int*)(ws + OFF_SPSRC);
    float* sp_w   = (float*)(ws + OFF_SPW);
    int*   g_off  = (int*)(ws + OFF_GOFF);
    int*   g_src  = (int*)(ws + OFF_GSRC);
    int*   cnt    = (int*)(ws + OFF_CNT);

    const dim3 b256(256);

    // ---- build CSR (by destination) for 5 scatter sets + GAT graph ----
    for (int s = 0; s < NSETS; ++s) {
        const int* si = scat_idx + (size_t)s * 2 * NE;
        hipMemsetAsync(cnt, 0, NN * 4, stream);
        count_dst<<<512, b256, 0, stream>>>(si + NE, NE, cnt);
        exscan30k<<<1, 1024, 0, stream>>>(cnt, sp_off + (size_t)s * (NN + 1));
        hipMemsetAsync(cnt, 0, NN * 4, stream);
        fill_sp<<<512, b256, 0, stream>>>(si, scat_w + (size_t)s * NE,
                                          sp_off + (size_t)s * (NN + 1), cnt,
                                          sp_src + (size_t)s * NE, sp_w + (size_t)s * NE);
    }
    hipMemsetAsync(cnt, 0, NN * 4, stream);
    count_gat<<<512, b256, 0, stream>>>(edge_ix, cnt);
    exscan30k<<<1, 1024, 0, stream>>>(cnt, g_off);
    hipMemsetAsync(cnt, 0, NN * 4, stream);
    fill_gat<<<512, b256, 0, stream>>>(edge_ix, g_off, cnt, g_src);

    // ---- h = x @ lin_W + lin_b ; x2 = h ----
    gemm64<512, 128, GM_LIN><<<dim3(469, 2), b256, 0, stream>>>(
        x, lin_W, lin_b, h, x2, nullptr, nullptr, nullptr, nullptr, NN);

    // ---- 5 GAT branches ----
    for (int i = 0; i < NSETS; ++i) {
        if (i == 0) {
            sp_gather<0><<<7500, b256, 0, stream>>>(sp_off, sp_src, sp_w, h, xcur);
        } else {
            sp_gather<1><<<7500, b256, 0, stream>>>(sp_off + (size_t)i * (NN + 1),
                                                    sp_src + (size_t)i * NE, sp_w + (size_t)i * NE, h, tmp);
            sp_gather<0><<<7500, b256, 0, stream>>>(sp_off, sp_src, sp_w, tmp, xcur);
        }
        gemm64<128, 512, GM_PLAIN><<<dim3(469, 8), b256, 0, stream>>>(
            xcur, gat_W + (size_t)i * 128 * 512, nullptr, hh, nullptr,
            nullptr, nullptr, nullptr, nullptr, NN);
        att_scores<<<7500, b256, 0, stream>>>(hh, att_src + (size_t)i * 512, att_dst + (size_t)i * 512,
                                              asrc, adst);
        att_mden<<<118, b256, 0, stream>>>(g_off, g_src, asrc, adst, mmax, dden);
        gat_agg<<<7500, b256, 0, stream>>>(g_off, g_src, asrc, adst, mmax, dden,
                                           hh, gat_b + (size_t)i * 512, gout);
        gemm64<512, 128, GM_MLP><<<dim3(469, 2), b256, 0, stream>>>(
            gout, mlp_W + (size_t)i * 512 * 128, mlp_b + (size_t)i * 128, nullptr, x2,
            bn_g + (size_t)i * 128, bn_b + (size_t)i * 128,
            bn_m + (size_t)i * 128, bn_v + (size_t)i * 128, NN);
    }

    // ---- out = log_softmax( elu(bn0(x2)) @ out_W + out_b ) ----
    final_out<<<7500, b256, 0, stream>>>(x2, bn0_g, bn0_b, bn0_m, bn0_v, out_W, out_b, out);
}

// Round 2
// 1389.423 us; speedup vs baseline: 1.7907x; 1.7907x over previous
//
#include <hip/hip_runtime.h>
#include <cstdint>
#include <cstddef>

// ---------------- problem constants ----------------
#define NN 30000        // nodes
#define NE 400000       // edges per scatter set
#define EG (NE + NN)    // GAT edges incl self loops
#define NSETS 5
#define NCLS 10
#define BN_EPS 1e-5f

typedef __bf16 bf16x8 __attribute__((ext_vector_type(8)));
typedef float  f32x4  __attribute__((ext_vector_type(4)));

// ---------------- workspace layout (bytes) ----------------
constexpr size_t alg(size_t x) { return (x + 255) & ~size_t(255); }
constexpr size_t OFF_XB    = 0;                                          // [N][512] bf16
constexpr size_t OFF_HB    = OFF_XB   + alg((size_t)NN * 512 * 2);       // [N][128] bf16
constexpr size_t OFF_X2    = OFF_HB   + alg((size_t)NN * 128 * 2);       // [N][128] f32 accumulator
constexpr size_t OFF_HH    = OFF_X2   + alg((size_t)NN * 128 * 4);       // [N][512] bf16
constexpr size_t OFF_GOUT  = OFF_HH   + alg((size_t)NN * 512 * 2);       // [N][512] bf16 (elu'd)
constexpr size_t OFF_XCUR  = OFF_GOUT + alg((size_t)NN * 512 * 2);       // [N][128] bf16
constexpr size_t OFF_TMP   = OFF_XCUR + alg((size_t)NN * 128 * 2);       // [N][128] bf16
constexpr size_t OFF_WT    = OFF_TMP  + alg((size_t)NN * 128 * 2);       // 11 * 65536 bf16
constexpr size_t OFF_AS    = OFF_WT   + alg((size_t)11 * 65536 * 2);
constexpr size_t OFF_AD    = OFF_AS   + alg((size_t)NN * 4 * 4);
constexpr size_t OFF_MM    = OFF_AD   + alg((size_t)NN * 4 * 4);
constexpr size_t OFF_DD    = OFF_MM   + alg((size_t)NN * 4 * 4);
constexpr size_t OFF_OFF6  = OFF_DD   + alg((size_t)NN * 4 * 4);         // 6*(NN+1) int
constexpr size_t OFF_SPSRC = OFF_OFF6 + alg((size_t)6 * (NN + 1) * 4);
constexpr size_t OFF_SPW   = OFF_SPSRC + alg((size_t)NSETS * NE * 4);
constexpr size_t OFF_GSRC  = OFF_SPW  + alg((size_t)NSETS * NE * 4);
constexpr size_t OFF_CNT   = OFF_GSRC + alg((size_t)EG * 4);             // 6*NN + 6*NN ints (cnt|cur)
constexpr size_t WS_NEED   = OFF_CNT  + alg((size_t)12 * NN * 4);        // ~154 MB

// ---------------- helpers ----------------
__device__ __forceinline__ float lrelu02(float v) { return v > 0.f ? v : 0.2f * v; }
__device__ __forceinline__ float eluf(float v)    { return v > 0.f ? v : __expf(v) - 1.f; }
__device__ __forceinline__ float bf2f(unsigned u) {
    union { unsigned i; float f; } c; c.i = u << 16; return c.f;
}
__device__ __forceinline__ unsigned short f2bf(float f) {
    union { float f; unsigned i; } c; c.f = f;
    unsigned u = c.i + 0x7FFFu + ((c.i >> 16) & 1u);
    return (unsigned short)(u >> 16);
}
__device__ __forceinline__ void gload_lds16(const void* g, void* l) {
    __builtin_amdgcn_global_load_lds(
        (const __attribute__((address_space(1))) void*)(uintptr_t)g,
        (__attribute__((address_space(3))) void*)(unsigned)(uintptr_t)l,
        16, 0, 0);
}

// ---------------- CSR build (fused over 5 sets + GAT graph) ----------------
__global__ void count_all(const int* __restrict__ scat_idx, const int* __restrict__ edge_ix,
                          int* __restrict__ cnt6) {
    const int total = NSETS * NE + EG;
    for (int i = blockIdx.x * blockDim.x + threadIdx.x; i < total; i += gridDim.x * blockDim.x) {
        if (i < NSETS * NE) {
            int s = i / NE, e = i - s * NE;
            atomicAdd(&cnt6[s * NN + scat_idx[(size_t)s * 2 * NE + NE + e]], 1);
        } else {
            int j = i - NSETS * NE;
            int d = (j < NE) ? edge_ix[NE + j] : (j - NE);
            atomicAdd(&cnt6[5 * NN + d], 1);
        }
    }
}

__global__ void exscan30k(const int* __restrict__ cnt6, int* __restrict__ off6) {
    const int* cnt = cnt6 + blockIdx.x * NN;
    int* off = off6 + blockIdx.x * (NN + 1);
    constexpr int per = 30;
    __shared__ int s[1024];
    const int t = threadIdx.x;
    const int base0 = t * per;
    int sum = 0;
    #pragma unroll
    for (int i = 0; i < per; ++i) { int idx = base0 + i; sum += (idx < NN) ? cnt[idx] : 0; }
    s[t] = sum;
    __syncthreads();
    for (int d = 1; d < 1024; d <<= 1) {
        int v = (t >= d) ? s[t - d] : 0;
        __syncthreads();
        s[t] += v;
        __syncthreads();
    }
    int run = s[t] - sum;
    #pragma unroll
    for (int i = 0; i < per; ++i) {
        int idx = base0 + i;
        if (idx < NN) { off[idx] = run; run += cnt[idx]; }
    }
    if (t == 1023) off[NN] = s[1023];
}

__global__ void fill_all(const int* __restrict__ scat_idx, const float* __restrict__ scat_w,
                         const int* __restrict__ edge_ix, const int* __restrict__ off6,
                         int* __restrict__ cur6, int* __restrict__ sp_src,
                         float* __restrict__ sp_w, int* __restrict__ g_src) {
    const int total = NSETS * NE + EG;
    for (int i = blockIdx.x * blockDim.x + threadIdx.x; i < total; i += gridDim.x * blockDim.x) {
        if (i < NSETS * NE) {
            int s = i / NE, e = i - s * NE;
            int d = scat_idx[(size_t)s * 2 * NE + NE + e];
            int p = off6[s * (NN + 1) + d] + atomicAdd(&cur6[s * NN + d], 1);
            sp_src[(size_t)s * NE + p] = scat_idx[(size_t)s * 2 * NE + e];
            sp_w[(size_t)s * NE + p]   = scat_w[(size_t)s * NE + e];
        } else {
            int j = i - NSETS * NE;
            int sidx, d;
            if (j < NE) { sidx = edge_ix[j]; d = edge_ix[NE + j]; }
            else        { sidx = j - NE;     d = sidx; }
            int p = off6[5 * (NN + 1) + d] + atomicAdd(&cur6[5 * NN + d], 1);
            g_src[p] = sidx;
        }
    }
}

// ---------------- conversions ----------------
__global__ void convx(const float* __restrict__ x, unsigned short* __restrict__ xb) {
    const int total = NN * 512 / 4;
    for (int i = blockIdx.x * blockDim.x + threadIdx.x; i < total; i += gridDim.x * blockDim.x) {
        float4 v = *(const float4*)(x + (size_t)i * 4);
        ushort4 o;
        o.x = f2bf(v.x); o.y = f2bf(v.y); o.z = f2bf(v.z); o.w = f2bf(v.w);
        *(ushort4*)(xb + (size_t)i * 4) = o;
    }
}

// W [B][K][N] f32 -> WT [B][N][K] bf16
__global__ void transW(const float* __restrict__ W, unsigned short* __restrict__ WT,
                       int Kd, int Nd, int B) {
    const int total = B * Kd * Nd;
    for (int i = blockIdx.x * blockDim.x + threadIdx.x; i < total; i += gridDim.x * blockDim.x) {
        int b = i / (Kd * Nd);
        int r = i - b * Kd * Nd;
        int n = r / Kd, k = r - n * Kd;
        WT[i] = f2bf(W[(size_t)b * Kd * Nd + (size_t)k * Nd + n]);
    }
}

// ---------------- MFMA bf16 GEMM: C[M][NC] = A[M][K] @ BT[NC][K]^T ----------------
// 64x128 block tile, BK=64, 4 waves (each 32x64), global_load_lds staging with
// XOR-swizzled global source (LDS layout: [row][(chunk ^ (row&7))*16B]).
template<int ROWS>
__device__ __forceinline__ void stage64(const unsigned short* __restrict__ src, int ld,
                                        int row0, int maxrow, int k0, char* lds, int t) {
    const int wave = t >> 6, lane = t & 63;
    const int sub = lane >> 3;                 // row within 8-row group
    const int kch = (lane & 7) ^ sub;          // swizzled 16B chunk (8 bf16)
    for (int j = wave; j < ROWS / 8; j += 4) {
        int grow = row0 + j * 8 + sub;
        if (grow > maxrow) grow = maxrow;
        gload_lds16(src + (size_t)grow * ld + k0 + kch * 8, lds + j * 1024);
    }
}

#define GM_LIN 0    // outb = bf16(A@B + bias); x2 = f32(same)
#define GM_PLAIN 1  // outb = bf16(A@B)
#define GM_MLP 2    // x2 += BN(A@B + bias)

template<int K, int NC, int MODE>
__global__ void __launch_bounds__(256) mgemm(const unsigned short* __restrict__ A,
                                             const unsigned short* __restrict__ BT,
                                             const float* __restrict__ bias,
                                             unsigned short* __restrict__ outb,
                                             float* __restrict__ x2,
                                             const float* __restrict__ bng, const float* __restrict__ bnb,
                                             const float* __restrict__ bnm, const float* __restrict__ bnv,
                                             int M) {
    __shared__ __align__(16) char As[64 * 128];    // [64][64] bf16 swizzled  (8 KB)
    __shared__ __align__(16) char Bs[128 * 128];   // [128][64] bf16 swizzled (16 KB)
    const int t = threadIdx.x, wave = t >> 6, lane = t & 63;
    const int bm = blockIdx.x * 64, bn = blockIdx.y * 128;
    const int wr = (wave >> 1) * 32, wc = (wave & 1) * 64;
    const int l15 = lane & 15, l4 = lane >> 4;
    const int rsw = (l15 & 7) << 4;                // read-side XOR term
    f32x4 acc[2][4] = {};

    for (int kt = 0; kt < K; kt += 64) {
        stage64<64>(A, K, bm, M - 1, kt, As, t);
        stage64<128>(BT, K, bn, NC - 1, kt, Bs, t);
        __syncthreads();
        #pragma unroll
        for (int kk = 0; kk < 2; ++kk) {
            bf16x8 af[2], bf[4];
            const int koff = kk * 64 + l4 * 16;
            #pragma unroll
            for (int fm = 0; fm < 2; ++fm) {
                int r = wr + fm * 16 + l15;
                af[fm] = *(const bf16x8*)(As + r * 128 + (koff ^ rsw));
            }
            #pragma unroll
            for (int fn = 0; fn < 4; ++fn) {
                int c = wc + fn * 16 + l15;
                bf[fn] = *(const bf16x8*)(Bs + c * 128 + (koff ^ rsw));
            }
            #pragma unroll
            for (int fm = 0; fm < 2; ++fm)
                #pragma unroll
                for (int fn = 0; fn < 4; ++fn)
                    acc[fm][fn] = __builtin_amdgcn_mfma_f32_16x16x32_bf16(af[fm], bf[fn], acc[fm][fn], 0, 0, 0);
        }
        __syncthreads();
    }

    #pragma unroll
    for (int fn = 0; fn < 4; ++fn) {
        const int c = bn + wc + fn * 16 + l15;
        float bias_c = 0.f, sc = 0.f, sh = 0.f;
        if constexpr (MODE == GM_LIN) bias_c = bias[c];
        if constexpr (MODE == GM_MLP) {
            bias_c = bias[c];
            sc = bng[c] * rsqrtf(bnv[c] + BN_EPS);
            sh = bnb[c] - bnm[c] * sc;
        }
        #pragma unroll
        for (int fm = 0; fm < 2; ++fm) {
            #pragma unroll
            for (int rg = 0; rg < 4; ++rg) {
                int r = bm + wr + fm * 16 + l4 * 4 + rg;
                if (r < M) {
                    float v = acc[fm][fn][rg];
                    if constexpr (MODE == GM_LIN) {
                        v += bias_c;
                        outb[(size_t)r * NC + c] = f2bf(v);
                        x2[(size_t)r * NC + c] = v;
                    } else if constexpr (MODE == GM_PLAIN) {
                        outb[(size_t)r * NC + c] = f2bf(v);
                    } else {
                        x2[(size_t)r * NC + c] += (v + bias_c) * sc + sh;
                    }
                }
            }
        }
    }
}

// ---------------- solo_pass gather: out[n] = [abs] sum_j w[j]*in[src[j]]  (bf16 128-ch) ----------------
template<int DO_ABS>
__global__ void __launch_bounds__(256) sp_gather(const int* __restrict__ off, const int* __restrict__ src,
                                                 const float* __restrict__ w,
                                                 const unsigned short* __restrict__ in,
                                                 unsigned short* __restrict__ out) {
    const int wid  = blockIdx.x * 4 + (threadIdx.x >> 6);
    const int lane = threadIdx.x & 63;
    const int s0 = off[wid], s1 = off[wid + 1];
    float a0 = 0.f, a1 = 0.f;
    for (int j = s0; j < s1; ++j) {
        const float wj = w[j];
        unsigned v = *(const unsigned*)(in + (size_t)src[j] * 128 + lane * 2);
        a0 = fmaf(wj, bf2f(v & 0xffffu), a0);
        a1 = fmaf(wj, bf2f(v >> 16), a1);
    }
    if (DO_ABS) { a0 = fabsf(a0); a1 = fabsf(a1); }
    unsigned o = (unsigned)f2bf(a0) | ((unsigned)f2bf(a1) << 16);
    *(unsigned*)(out + (size_t)wid * 128 + lane * 2) = o;
}

// ---------------- GAT attention scores ----------------
__global__ void __launch_bounds__(256) att_scores(const unsigned short* __restrict__ hh,
                                                  const float* __restrict__ att_s, const float* __restrict__ att_d,
                                                  float* __restrict__ as_, float* __restrict__ ad_) {
    __shared__ float ss[512], sd[512];
    for (int i = threadIdx.x; i < 512; i += 256) { ss[i] = att_s[i]; sd[i] = att_d[i]; }
    __syncthreads();
    const int wid  = blockIdx.x * 4 + (threadIdx.x >> 6);
    const int lane = threadIdx.x & 63;
    uint4 v = *(const uint4*)(hh + (size_t)wid * 512 + lane * 8);
    float f[8];
    f[0] = bf2f(v.x & 0xffffu); f[1] = bf2f(v.x >> 16);
    f[2] = bf2f(v.y & 0xffffu); f[3] = bf2f(v.y >> 16);
    f[4] = bf2f(v.z & 0xffffu); f[5] = bf2f(v.z >> 16);
    f[6] = bf2f(v.w & 0xffffu); f[7] = bf2f(v.w >> 16);
    float ps = 0.f, pd = 0.f;
    #pragma unroll
    for (int c = 0; c < 8; ++c) {
        ps = fmaf(f[c], ss[lane * 8 + c], ps);
        pd = fmaf(f[c], sd[lane * 8 + c], pd);
    }
    #pragma unroll
    for (int d = 1; d < 16; d <<= 1) { ps += __shfl_xor(ps, d); pd += __shfl_xor(pd, d); }
    if ((lane & 15) == 0) {
        const int hd = lane >> 4;
        as_[(size_t)wid * 4 + hd] = ps;
        ad_[(size_t)wid * 4 + hd] = pd;
    }
}

// ---------------- per-dst segment max + exp-sum ----------------
__global__ void att_mden(const int* __restrict__ goff, const int* __restrict__ gsrc,
                         const float* __restrict__ as_, const float* __restrict__ ad_,
                         float* __restrict__ mmax, float* __restrict__ dden) {
    const int n = blockIdx.x * 256 + threadIdx.x;
    if (n >= NN) return;
    const int s0 = goff[n], s1 = goff[n + 1];
    float4 adv = *(const float4*)(ad_ + (size_t)n * 4);
    float m0 = -1e30f, m1 = -1e30f, m2 = -1e30f, m3 = -1e30f;
    for (int j = s0; j < s1; ++j) {
        int s = gsrc[j];
        float4 av = *(const float4*)(as_ + (size_t)s * 4);
        m0 = fmaxf(m0, lrelu02(av.x + adv.x));
        m1 = fmaxf(m1, lrelu02(av.y + adv.y));
        m2 = fmaxf(m2, lrelu02(av.z + adv.z));
        m3 = fmaxf(m3, lrelu02(av.w + adv.w));
    }
    float d0 = 0.f, d1 = 0.f, d2 = 0.f, d3 = 0.f;
    for (int j = s0; j < s1; ++j) {
        int s = gsrc[j];
        float4 av = *(const float4*)(as_ + (size_t)s * 4);
        d0 += __expf(lrelu02(av.x + adv.x) - m0);
        d1 += __expf(lrelu02(av.y + adv.y) - m1);
        d2 += __expf(lrelu02(av.z + adv.z) - m2);
        d3 += __expf(lrelu02(av.w + adv.w) - m3);
    }
    *(float4*)(mmax + (size_t)n * 4) = make_float4(m0, m1, m2, m3);
    *(float4*)(dden + (size_t)n * 4) = make_float4(d0, d1, d2, d3);
}

// ---------------- GAT aggregation + bias + ELU -> bf16 gout ----------------
__global__ void __launch_bounds__(256) gat_agg(const int* __restrict__ goff, const int* __restrict__ gsrc,
                                               const float* __restrict__ as_, const float* __restrict__ ad_,
                                               const float* __restrict__ mmax, const float* __restrict__ dden,
                                               const unsigned short* __restrict__ hh,
                                               const float* __restrict__ gat_b,
                                               unsigned short* __restrict__ gout) {
    const int wid  = blockIdx.x * 4 + (threadIdx.x >> 6);
    const int lane = threadIdx.x & 63;
    const int hd   = lane >> 4;
    const float adv = ad_[(size_t)wid * 4 + hd];
    const float mv  = mmax[(size_t)wid * 4 + hd];
    const float inv = 1.f / (dden[(size_t)wid * 4 + hd] + 1e-16f);
    const int s0 = goff[wid], s1 = goff[wid + 1];
    float a[8] = {};
    for (int j = s0; j < s1; ++j) {
        const int s = gsrc[j];
        float e = lrelu02(as_[(size_t)s * 4 + hd] + adv);
        float alpha = __expf(e - mv) * inv;
        uint4 v = *(const uint4*)(hh + (size_t)s * 512 + lane * 8);
        a[0] = fmaf(alpha, bf2f(v.x & 0xffffu), a[0]); a[1] = fmaf(alpha, bf2f(v.x >> 16), a[1]);
        a[2] = fmaf(alpha, bf2f(v.y & 0xffffu), a[2]); a[3] = fmaf(alpha, bf2f(v.y >> 16), a[3]);
        a[4] = fmaf(alpha, bf2f(v.z & 0xffffu), a[4]); a[5] = fmaf(alpha, bf2f(v.z >> 16), a[5]);
        a[6] = fmaf(alpha, bf2f(v.w & 0xffffu), a[6]); a[7] = fmaf(alpha, bf2f(v.w >> 16), a[7]);
    }
    unsigned short o[8];
    #pragma unroll
    for (int c = 0; c < 8; ++c)
        o[c] = f2bf(eluf(a[c] + gat_b[lane * 8 + c]));
    uint4 ov;
    ov.x = (unsigned)o[0] | ((unsigned)o[1] << 16);
    ov.y = (unsigned)o[2] | ((unsigned)o[3] << 16);
    ov.z = (unsigned)o[4] | ((unsigned)o[5] << 16);
    ov.w = (unsigned)o[6] | ((unsigned)o[7] << 16);
    *(uint4*)(gout + (size_t)wid * 512 + lane * 8) = ov;
}

// ---------------- final: out = log_softmax( elu(bn0(x2)) @ outW + outb ) ----------------
__global__ void __launch_bounds__(256) final_out(const float* __restrict__ x2,
                                                 const float* __restrict__ bn0g, const float* __restrict__ bn0b,
                                                 const float* __restrict__ bn0m, const float* __restrict__ bn0v,
                                                 const float* __restrict__ outW, const float* __restrict__ outb,
                                                 float* __restrict__ out) {
    __shared__ float sW[128 * 12];
    __shared__ float sSc[128], sSh[128];
    for (int i = threadIdx.x; i < 1280; i += 256) {
        int r = i / 10, c = i - r * 10;
        sW[r * 12 + c] = outW[i];
    }
    if (threadIdx.x < 128) {
        int c = threadIdx.x;
        float sc = bn0g[c] * rsqrtf(bn0v[c] + BN_EPS);
        sSc[c] = sc;
        sSh[c] = bn0b[c] - bn0m[c] * sc;
    }
    __syncthreads();
    const int wid  = blockIdx.x * 4 + (threadIdx.x >> 6);
    const int lane = threadIdx.x & 63;
    const int c0 = lane * 2;
    float2 a = *(const float2*)(x2 + (size_t)wid * 128 + c0);
    float a0 = eluf(a.x * sSc[c0] + sSh[c0]);
    float a1 = eluf(a.y * sSc[c0 + 1] + sSh[c0 + 1]);
    float p[NCLS];
    #pragma unroll
    for (int j = 0; j < NCLS; ++j)
        p[j] = a0 * sW[c0 * 12 + j] + a1 * sW[(c0 + 1) * 12 + j];
    #pragma unroll
    for (int j = 0; j < NCLS; ++j) {
        float v = p[j];
        v += __shfl_xor(v, 1);  v += __shfl_xor(v, 2);  v += __shfl_xor(v, 4);
        v += __shfl_xor(v, 8);  v += __shfl_xor(v, 16); v += __shfl_xor(v, 32);
        p[j] = v;
    }
    float z[NCLS];
    #pragma unroll
    for (int j = 0; j < NCLS; ++j) z[j] = p[j] + outb[j];
    float m = z[0];
    #pragma unroll
    for (int j = 1; j < NCLS; ++j) m = fmaxf(m, z[j]);
    float ssum = 0.f;
    #pragma unroll
    for (int j = 0; j < NCLS; ++j) ssum += __expf(z[j] - m);
    float lse = m + __logf(ssum);
    #pragma unroll
    for (int j = 0; j < NCLS; ++j)
        if (lane == j) out[(size_t)wid * NCLS + j] = z[j] - lse;
}

// ---------------- launcher ----------------
extern "C" void kernel_launch(void* const* d_in, const int* in_sizes, int n_in,
                              void* d_out, int out_size, void* d_ws, size_t ws_size,
                              hipStream_t stream) {
    const float* x        = (const float*)d_in[0];
    const int*   edge_ix  = (const int*)  d_in[1];
    const int*   scat_idx = (const int*)  d_in[2];
    const float* scat_w   = (const float*)d_in[3];
    const float* lin_W    = (const float*)d_in[4];
    const float* lin_b    = (const float*)d_in[5];
    const float* gat_W    = (const float*)d_in[6];
    const float* att_src  = (const float*)d_in[7];
    const float* att_dst  = (const float*)d_in[8];
    const float* gat_b    = (const float*)d_in[9];
    const float* mlp_W    = (const float*)d_in[10];
    const float* mlp_b    = (const float*)d_in[11];
    const float* bn_g     = (const float*)d_in[12];
    const float* bn_b     = (const float*)d_in[13];
    const float* bn_m     = (const float*)d_in[14];
    const float* bn_v     = (const float*)d_in[15];
    const float* bn0_g    = (const float*)d_in[16];
    const float* bn0_b    = (const float*)d_in[17];
    const float* bn0_m    = (const float*)d_in[18];
    const float* bn0_v    = (const float*)d_in[19];
    const float* out_W    = (const float*)d_in[20];
    const float* out_b    = (const float*)d_in[21];
    float* out = (float*)d_out;

    char* ws = (char*)d_ws;
    unsigned short* xb    = (unsigned short*)(ws + OFF_XB);
    unsigned short* hb    = (unsigned short*)(ws + OFF_HB);
    float*          x2    = (float*)(ws + OFF_X2);
    unsigned short* hh    = (unsigned short*)(ws + OFF_HH);
    unsigned short* gout  = (unsigned short*)(ws + OFF_GOUT);
    unsigned short* xcur  = (unsigned short*)(ws + OFF_XCUR);
    unsigned short* tmp   = (unsigned short*)(ws + OFF_TMP);
    unsigned short* wt    = (unsigned short*)(ws + OFF_WT);
    unsigned short* linWT = wt;                         // [128][512]
    unsigned short* gatWT = wt + 65536;                 // [5][512][128]
    unsigned short* mlpWT = wt + 65536 * 6;             // [5][128][512]
    float* asrc = (float*)(ws + OFF_AS);
    float* adst = (float*)(ws + OFF_AD);
    float* mmax = (float*)(ws + OFF_MM);
    float* dden = (float*)(ws + OFF_DD);
    int*   off6   = (int*)(ws + OFF_OFF6);
    int*   sp_src = (int*)(ws + OFF_SPSRC);
    float* sp_w   = (float*)(ws + OFF_SPW);
    int*   g_src  = (int*)(ws + OFF_GSRC);
    int*   cnt6   = (int*)(ws + OFF_CNT);
    int*   cur6   = cnt6 + 6 * NN;

    const dim3 b256(256);

    // ---- CSR build (all 6 graphs) ----
    hipMemsetAsync(cnt6, 0, (size_t)12 * NN * 4, stream);
    count_all<<<2048, b256, 0, stream>>>(scat_idx, edge_ix, cnt6);
    exscan30k<<<6, 1024, 0, stream>>>(cnt6, off6);
    fill_all<<<2048, b256, 0, stream>>>(scat_idx, scat_w, edge_ix, off6, cur6, sp_src, sp_w, g_src);

    // ---- dtype conversions ----
    convx<<<2048, b256, 0, stream>>>(x, xb);
    transW<<<256, b256, 0, stream>>>(lin_W, linWT, 512, 128, 1);
    transW<<<640, b256, 0, stream>>>(gat_W, gatWT, 128, 512, 5);
    transW<<<640, b256, 0, stream>>>(mlp_W, mlpWT, 512, 128, 5);

    // ---- h = x @ lin_W + lin_b (bf16 out) ; x2 = h (f32) ----
    mgemm<512, 128, GM_LIN><<<dim3(469, 1), b256, 0, stream>>>(
        xb, linWT, lin_b, hb, x2, nullptr, nullptr, nullptr, nullptr, NN);

    // ---- 5 GAT branches ----
    for (int i = 0; i < NSETS; ++i) {
        const int* spo = off6 + i * (NN + 1);
        if (i == 0) {
            sp_gather<0><<<7500, b256, 0, stream>>>(off6, sp_src, sp_w, hb, xcur);
        } else {
            sp_gather<1><<<7500, b256, 0, stream>>>(spo, sp_src + (size_t)i * NE, sp_w + (size_t)i * NE, hb, tmp);
            sp_gather<0><<<7500, b256, 0, stream>>>(off6, sp_src, sp_w, tmp, xcur);
        }
        mgemm<128, 512, GM_PLAIN><<<dim3(469, 4), b256, 0, stream>>>(
            xcur, gatWT + (size_t)i * 65536, nullptr, hh, nullptr,
            nullptr, nullptr, nullptr, nullptr, NN);
        att_scores<<<7500, b256, 0, stream>>>(hh, att_src + (size_t)i * 512, att_dst + (size_t)i * 512,
                                              asrc, adst);
        att_mden<<<118, b256, 0, stream>>>(off6 + 5 * (NN + 1), g_src, asrc, adst, mmax, dden);
        gat_agg<<<7500, b256, 0, stream>>>(off6 + 5 * (NN + 1), g_src, asrc, adst, mmax, dden,
                                           hh, gat_b + (size_t)i * 512, gout);
        mgemm<512, 128, GM_MLP><<<dim3(469, 1), b256, 0, stream>>>(
            gout, mlpWT + (size_t)i * 65536, mlp_b + (size_t)i * 128, nullptr, x2,
            bn_g + (size_t)i * 128, bn_b + (size_t)i * 128,
            bn_m + (size_t)i * 128, bn_v + (size_t)i * 128, NN);
    }

    // ---- final ----
    final_out<<<7500, b256, 0, stream>>>(x2, bn0_g, bn0_b, bn0_m, bn0_v, out_W, out_b, out);
}

// Round 3
// 1252.085 us; speedup vs baseline: 1.9871x; 1.1097x over previous
//
#include <hip/hip_runtime.h>
#include <cstdint>
#include <cstddef>

// ---------------- problem constants ----------------
#define NN 30000        // nodes
#define NE 400000       // edges per scatter set
#define EG (NE + NN)    // GAT edges incl self loops
#define NSETS 5
#define NCLS 10
#define BN_EPS 1e-5f

typedef __bf16 bf16x8 __attribute__((ext_vector_type(8)));
typedef float  f32x4  __attribute__((ext_vector_type(4)));

// ---------------- workspace layout (bytes) ----------------
// U1:   xb [N][512]bf16 (30.72MB, dead after LIN gemm) / xcur5 [5][N][128]bf16 (38.4MB)
// GOUT: gout [N][512]bf16  aliased with tmp4 [4][N][128]bf16 (tmp dead before gat_agg)
// CNT:  cnt6|cur6 ints (CSR build) aliased with as_/ad_ (used after build)
constexpr size_t alg(size_t x) { return (x + 255) & ~size_t(255); }
constexpr size_t OFF_U1    = 0;                                           // 38,400,000
constexpr size_t OFF_HB    = OFF_U1   + alg((size_t)5 * NN * 128 * 2);    // 7,680,000
constexpr size_t OFF_X2    = OFF_HB   + alg((size_t)NN * 128 * 2);        // 15,360,000
constexpr size_t OFF_HH    = OFF_X2   + alg((size_t)NN * 128 * 4);        // 30,720,000
constexpr size_t OFF_GOUT  = OFF_HH   + alg((size_t)NN * 512 * 2);        // 30,720,000
constexpr size_t OFF_WT    = OFF_GOUT + alg((size_t)NN * 512 * 2);        // 1,441,792
constexpr size_t OFF_OFF6  = OFF_WT   + alg((size_t)11 * 65536 * 2);      // 720,024
constexpr size_t OFF_SPP   = OFF_OFF6 + alg((size_t)6 * (NN + 1) * 4);    // 16,000,000 packed (src,w)
constexpr size_t OFF_GSRC  = OFF_SPP  + alg((size_t)NSETS * NE * 8);      // 1,720,000
constexpr size_t OFF_CNT   = OFF_GSRC + alg((size_t)EG * 4);              // 1,440,000
constexpr size_t WS_NEED   = OFF_CNT  + alg((size_t)12 * NN * 4);         // ~144.2 MB

// ---------------- helpers ----------------
__device__ __forceinline__ float lrelu02(float v) { return v > 0.f ? v : 0.2f * v; }
__device__ __forceinline__ float eluf(float v)    { return v > 0.f ? v : __expf(v) - 1.f; }
__device__ __forceinline__ float bf2f(unsigned u) {
    union { unsigned i; float f; } c; c.i = u << 16; return c.f;
}
__device__ __forceinline__ unsigned short f2bf(float f) {
    union { float f; unsigned i; } c; c.f = f;
    unsigned u = c.i + 0x7FFFu + ((c.i >> 16) & 1u);
    return (unsigned short)(u >> 16);
}
__device__ __forceinline__ void gload_lds16(const void* g, void* l) {
    __builtin_amdgcn_global_load_lds(
        (const __attribute__((address_space(1))) void*)(uintptr_t)g,
        (__attribute__((address_space(3))) void*)(unsigned)(uintptr_t)l,
        16, 0, 0);
}

// ---------------- CSR build (fused over 5 sets + GAT graph) ----------------
__global__ void count_all(const int* __restrict__ scat_idx, const int* __restrict__ edge_ix,
                          int* __restrict__ cnt6) {
    const int total = NSETS * NE + EG;
    for (int i = blockIdx.x * blockDim.x + threadIdx.x; i < total; i += gridDim.x * blockDim.x) {
        if (i < NSETS * NE) {
            int s = i / NE, e = i - s * NE;
            atomicAdd(&cnt6[s * NN + scat_idx[(size_t)s * 2 * NE + NE + e]], 1);
        } else {
            int j = i - NSETS * NE;
            int d = (j < NE) ? edge_ix[NE + j] : (j - NE);
            atomicAdd(&cnt6[5 * NN + d], 1);
        }
    }
}

__global__ void exscan30k(const int* __restrict__ cnt6, int* __restrict__ off6) {
    const int* cnt = cnt6 + blockIdx.x * NN;
    int* off = off6 + blockIdx.x * (NN + 1);
    constexpr int per = 30;
    __shared__ int s[1024];
    const int t = threadIdx.x;
    const int base0 = t * per;
    int sum = 0;
    #pragma unroll
    for (int i = 0; i < per; ++i) { int idx = base0 + i; sum += (idx < NN) ? cnt[idx] : 0; }
    s[t] = sum;
    __syncthreads();
    for (int d = 1; d < 1024; d <<= 1) {
        int v = (t >= d) ? s[t - d] : 0;
        __syncthreads();
        s[t] += v;
        __syncthreads();
    }
    int run = s[t] - sum;
    #pragma unroll
    for (int i = 0; i < per; ++i) {
        int idx = base0 + i;
        if (idx < NN) { off[idx] = run; run += cnt[idx]; }
    }
    if (t == 1023) off[NN] = s[1023];
}

__global__ void fill_all(const int* __restrict__ scat_idx, const float* __restrict__ scat_w,
                         const int* __restrict__ edge_ix, const int* __restrict__ off6,
                         int* __restrict__ cur6, int2* __restrict__ spp,
                         int* __restrict__ g_src) {
    const int total = NSETS * NE + EG;
    for (int i = blockIdx.x * blockDim.x + threadIdx.x; i < total; i += gridDim.x * blockDim.x) {
        if (i < NSETS * NE) {
            int s = i / NE, e = i - s * NE;
            int d = scat_idx[(size_t)s * 2 * NE + NE + e];
            int p = off6[s * (NN + 1) + d] + atomicAdd(&cur6[s * NN + d], 1);
            int2 pk;
            pk.x = scat_idx[(size_t)s * 2 * NE + e];
            pk.y = __float_as_int(scat_w[(size_t)s * NE + e]);
            spp[(size_t)s * NE + p] = pk;
        } else {
            int j = i - NSETS * NE;
            int sidx, d;
            if (j < NE) { sidx = edge_ix[j]; d = edge_ix[NE + j]; }
            else        { sidx = j - NE;     d = sidx; }
            int p = off6[5 * (NN + 1) + d] + atomicAdd(&cur6[5 * NN + d], 1);
            g_src[p] = sidx;
        }
    }
}

// ---------------- conversions ----------------
__global__ void convx(const float* __restrict__ x, unsigned short* __restrict__ xb) {
    const int total = NN * 512 / 4;
    for (int i = blockIdx.x * blockDim.x + threadIdx.x; i < total; i += gridDim.x * blockDim.x) {
        float4 v = *(const float4*)(x + (size_t)i * 4);
        ushort4 o;
        o.x = f2bf(v.x); o.y = f2bf(v.y); o.z = f2bf(v.z); o.w = f2bf(v.w);
        *(ushort4*)(xb + (size_t)i * 4) = o;
    }
}

// W [B][K][N] f32 -> WT [B][N][K] bf16
__global__ void transW(const float* __restrict__ W, unsigned short* __restrict__ WT,
                       int Kd, int Nd, int B) {
    const int total = B * Kd * Nd;
    for (int i = blockIdx.x * blockDim.x + threadIdx.x; i < total; i += gridDim.x * blockDim.x) {
        int b = i / (Kd * Nd);
        int r = i - b * Kd * Nd;
        int n = r / Kd, k = r - n * Kd;
        WT[i] = f2bf(W[(size_t)b * Kd * Nd + (size_t)k * Nd + n]);
    }
}

// ---------------- MFMA bf16 GEMM: C[M][NC] = A[M][K] @ BT[NC][K]^T ----------------
template<int ROWS>
__device__ __forceinline__ void stage64(const unsigned short* __restrict__ src, int ld,
                                        int row0, int maxrow, int k0, char* lds, int t) {
    const int wave = t >> 6, lane = t & 63;
    const int sub = lane >> 3;                 // row within 8-row group
    const int kch = (lane & 7) ^ sub;          // swizzled 16B chunk (8 bf16)
    for (int j = wave; j < ROWS / 8; j += 4) {
        int grow = row0 + j * 8 + sub;
        if (grow > maxrow) grow = maxrow;
        gload_lds16(src + (size_t)grow * ld + k0 + kch * 8, lds + j * 1024);
    }
}

#define GM_LIN 0    // outb = bf16(A@B + bias); x2 = f32(same)
#define GM_PLAIN 1  // outb = bf16(A@B)
#define GM_MLP 2    // x2 += BN(A@B + bias)

template<int K, int NC, int MODE>
__global__ void __launch_bounds__(256) mgemm(const unsigned short* __restrict__ A,
                                             const unsigned short* __restrict__ BT,
                                             const float* __restrict__ bias,
                                             unsigned short* __restrict__ outb,
                                             float* __restrict__ x2,
                                             const float* __restrict__ bng, const float* __restrict__ bnb,
                                             const float* __restrict__ bnm, const float* __restrict__ bnv,
                                             int M) {
    __shared__ __align__(16) char As[64 * 128];    // [64][64] bf16 swizzled  (8 KB)
    __shared__ __align__(16) char Bs[128 * 128];   // [128][64] bf16 swizzled (16 KB)
    const int t = threadIdx.x, wave = t >> 6, lane = t & 63;
    const int bm = blockIdx.x * 64, bn = blockIdx.y * 128;
    const int wr = (wave >> 1) * 32, wc = (wave & 1) * 64;
    const int l15 = lane & 15, l4 = lane >> 4;
    const int rsw = (l15 & 7) << 4;                // read-side XOR term
    f32x4 acc[2][4] = {};

    for (int kt = 0; kt < K; kt += 64) {
        stage64<64>(A, K, bm, M - 1, kt, As, t);
        stage64<128>(BT, K, bn, NC - 1, kt, Bs, t);
        __syncthreads();
        #pragma unroll
        for (int kk = 0; kk < 2; ++kk) {
            bf16x8 af[2], bf[4];
            const int koff = kk * 64 + l4 * 16;
            #pragma unroll
            for (int fm = 0; fm < 2; ++fm) {
                int r = wr + fm * 16 + l15;
                af[fm] = *(const bf16x8*)(As + r * 128 + (koff ^ rsw));
            }
            #pragma unroll
            for (int fn = 0; fn < 4; ++fn) {
                int c = wc + fn * 16 + l15;
                bf[fn] = *(const bf16x8*)(Bs + c * 128 + (koff ^ rsw));
            }
            #pragma unroll
            for (int fm = 0; fm < 2; ++fm)
                #pragma unroll
                for (int fn = 0; fn < 4; ++fn)
                    acc[fm][fn] = __builtin_amdgcn_mfma_f32_16x16x32_bf16(af[fm], bf[fn], acc[fm][fn], 0, 0, 0);
        }
        __syncthreads();
    }

    #pragma unroll
    for (int fn = 0; fn < 4; ++fn) {
        const int c = bn + wc + fn * 16 + l15;
        float bias_c = 0.f, sc = 0.f, sh = 0.f;
        if constexpr (MODE == GM_LIN) bias_c = bias[c];
        if constexpr (MODE == GM_MLP) {
            bias_c = bias[c];
            sc = bng[c] * rsqrtf(bnv[c] + BN_EPS);
            sh = bnb[c] - bnm[c] * sc;
        }
        #pragma unroll
        for (int fm = 0; fm < 2; ++fm) {
            #pragma unroll
            for (int rg = 0; rg < 4; ++rg) {
                int r = bm + wr + fm * 16 + l4 * 4 + rg;
                if (r < M) {
                    float v = acc[fm][fn][rg];
                    if constexpr (MODE == GM_LIN) {
                        v += bias_c;
                        outb[(size_t)r * NC + c] = f2bf(v);
                        x2[(size_t)r * NC + c] = v;
                    } else if constexpr (MODE == GM_PLAIN) {
                        outb[(size_t)r * NC + c] = f2bf(v);
                    } else {
                        x2[(size_t)r * NC + c] += (v + bias_c) * sc + sh;
                    }
                }
            }
        }
    }
}

// ---------------- batched solo_pass gathers ----------------
// PHASE 0: tmp_y = abs(sp(y+1, hb)), y=0..3.  PHASE 1: xcur_y = sp(0, y==0? hb : tmp_{y-1}), y=0..4.
template<int PHASE>
__global__ void __launch_bounds__(256) sp_batch(const int* __restrict__ off6,
                                                const int2* __restrict__ spp,
                                                const unsigned short* __restrict__ hb,
                                                const unsigned short* __restrict__ tmp,
                                                unsigned short* __restrict__ outb) {
    const int y = blockIdx.y;
    const int* off; const int2* pk; const unsigned short* in;
    if constexpr (PHASE == 0) {
        off = off6 + (y + 1) * (NN + 1);
        pk  = spp + (size_t)(y + 1) * NE;
        in  = hb;
    } else {
        off = off6;
        pk  = spp;
        in  = (y == 0) ? hb : tmp + (size_t)(y - 1) * NN * 128;
    }
    unsigned short* out = outb + (size_t)y * NN * 128;

    const int wid  = blockIdx.x * 4 + (threadIdx.x >> 6);
    const int lane = threadIdx.x & 63;
    const int s0 = off[wid], s1 = off[wid + 1];
    float a0 = 0.f, a1 = 0.f;
    for (int j = s0; j < s1; ++j) {
        int2 e = pk[j];
        const float wj = __int_as_float(e.y);
        unsigned v = *(const unsigned*)(in + (size_t)e.x * 128 + lane * 2);
        a0 = fmaf(wj, bf2f(v & 0xffffu), a0);
        a1 = fmaf(wj, bf2f(v >> 16), a1);
    }
    if constexpr (PHASE == 0) { a0 = fabsf(a0); a1 = fabsf(a1); }
    unsigned o = (unsigned)f2bf(a0) | ((unsigned)f2bf(a1) << 16);
    *(unsigned*)(out + (size_t)wid * 128 + lane * 2) = o;
}

// ---------------- GAT attention scores ----------------
__global__ void __launch_bounds__(256) att_scores(const unsigned short* __restrict__ hh,
                                                  const float* __restrict__ att_s, const float* __restrict__ att_d,
                                                  float* __restrict__ as_, float* __restrict__ ad_) {
    __shared__ float ss[512], sd[512];
    for (int i = threadIdx.x; i < 512; i += 256) { ss[i] = att_s[i]; sd[i] = att_d[i]; }
    __syncthreads();
    const int wid  = blockIdx.x * 4 + (threadIdx.x >> 6);
    const int lane = threadIdx.x & 63;
    uint4 v = *(const uint4*)(hh + (size_t)wid * 512 + lane * 8);
    float f[8];
    f[0] = bf2f(v.x & 0xffffu); f[1] = bf2f(v.x >> 16);
    f[2] = bf2f(v.y & 0xffffu); f[3] = bf2f(v.y >> 16);
    f[4] = bf2f(v.z & 0xffffu); f[5] = bf2f(v.z >> 16);
    f[6] = bf2f(v.w & 0xffffu); f[7] = bf2f(v.w >> 16);
    float ps = 0.f, pd = 0.f;
    #pragma unroll
    for (int c = 0; c < 8; ++c) {
        ps = fmaf(f[c], ss[lane * 8 + c], ps);
        pd = fmaf(f[c], sd[lane * 8 + c], pd);
    }
    #pragma unroll
    for (int d = 1; d < 16; d <<= 1) { ps += __shfl_xor(ps, d); pd += __shfl_xor(pd, d); }
    if ((lane & 15) == 0) {
        const int hd = lane >> 4;
        as_[(size_t)wid * 4 + hd] = ps;
        ad_[(size_t)wid * 4 + hd] = pd;
    }
}

// ---------------- GAT aggregation (fused online softmax) + bias + ELU -> bf16 gout ----------------
__global__ void __launch_bounds__(256) gat_agg(const int* __restrict__ goff, const int* __restrict__ gsrc,
                                               const float* __restrict__ as_, const float* __restrict__ ad_,
                                               const unsigned short* __restrict__ hh,
                                               const float* __restrict__ gat_b,
                                               unsigned short* __restrict__ gout) {
    const int wid  = blockIdx.x * 4 + (threadIdx.x >> 6);
    const int lane = threadIdx.x & 63;
    const int s0 = goff[wid], s1 = goff[wid + 1];
    const float4 adv4 = *(const float4*)(ad_ + (size_t)wid * 4);

    // phase 1: online max + exp-sum per head, all 64 lanes over edge subsets
    float m[4] = {-1e30f, -1e30f, -1e30f, -1e30f};
    float s[4] = {0.f, 0.f, 0.f, 0.f};
    for (int j = s0 + lane; j < s1; j += 64) {
        const int si = gsrc[j];
        float4 av = *(const float4*)(as_ + (size_t)si * 4);
        float e0 = lrelu02(av.x + adv4.x), e1 = lrelu02(av.y + adv4.y);
        float e2 = lrelu02(av.z + adv4.z), e3 = lrelu02(av.w + adv4.w);
        float e[4] = {e0, e1, e2, e3};
        #pragma unroll
        for (int h = 0; h < 4; ++h) {
            if (e[h] > m[h]) { s[h] = s[h] * __expf(m[h] - e[h]) + 1.f; m[h] = e[h]; }
            else             { s[h] += __expf(e[h] - m[h]); }
        }
    }
    #pragma unroll
    for (int d = 1; d < 64; d <<= 1) {
        #pragma unroll
        for (int h = 0; h < 4; ++h) {
            float om = __shfl_xor(m[h], d);
            float os = __shfl_xor(s[h], d);
            float nm = fmaxf(m[h], om);
            s[h] = s[h] * __expf(m[h] - nm) + os * __expf(om - nm);
            m[h] = nm;
        }
    }
    const int hd = lane >> 4;
    const float advh = hd == 0 ? adv4.x : hd == 1 ? adv4.y : hd == 2 ? adv4.z : adv4.w;
    const float mv   = hd == 0 ? m[0]   : hd == 1 ? m[1]   : hd == 2 ? m[2]   : m[3];
    const float dv   = hd == 0 ? s[0]   : hd == 1 ? s[1]   : hd == 2 ? s[2]   : s[3];
    const float inv  = 1.f / (dv + 1e-16f);

    // phase 2: channel accumulation
    float a[8] = {};
    for (int j = s0; j < s1; ++j) {
        const int si = gsrc[j];
        float e = lrelu02(as_[(size_t)si * 4 + hd] + advh);
        float alpha = __expf(e - mv) * inv;
        uint4 v = *(const uint4*)(hh + (size_t)si * 512 + lane * 8);
        a[0] = fmaf(alpha, bf2f(v.x & 0xffffu), a[0]); a[1] = fmaf(alpha, bf2f(v.x >> 16), a[1]);
        a[2] = fmaf(alpha, bf2f(v.y & 0xffffu), a[2]); a[3] = fmaf(alpha, bf2f(v.y >> 16), a[3]);
        a[4] = fmaf(alpha, bf2f(v.z & 0xffffu), a[4]); a[5] = fmaf(alpha, bf2f(v.z >> 16), a[5]);
        a[6] = fmaf(alpha, bf2f(v.w & 0xffffu), a[6]); a[7] = fmaf(alpha, bf2f(v.w >> 16), a[7]);
    }
    unsigned short o[8];
    #pragma unroll
    for (int c = 0; c < 8; ++c)
        o[c] = f2bf(eluf(a[c] + gat_b[lane * 8 + c]));
    uint4 ov;
    ov.x = (unsigned)o[0] | ((unsigned)o[1] << 16);
    ov.y = (unsigned)o[2] | ((unsigned)o[3] << 16);
    ov.z = (unsigned)o[4] | ((unsigned)o[5] << 16);
    ov.w = (unsigned)o[6] | ((unsigned)o[7] << 16);
    *(uint4*)(gout + (size_t)wid * 512 + lane * 8) = ov;
}

// ---------------- final: out = log_softmax( elu(bn0(x2)) @ outW + outb ) ----------------
__global__ void __launch_bounds__(256) final_out(const float* __restrict__ x2,
                                                 const float* __restrict__ bn0g, const float* __restrict__ bn0b,
                                                 const float* __restrict__ bn0m, const float* __restrict__ bn0v,
                                                 const float* __restrict__ outW, const float* __restrict__ outb,
                                                 float* __restrict__ out) {
    __shared__ float sW[128 * 12];
    __shared__ float sSc[128], sSh[128];
    for (int i = threadIdx.x; i < 1280; i += 256) {
        int r = i / 10, c = i - r * 10;
        sW[r * 12 + c] = outW[i];
    }
    if (threadIdx.x < 128) {
        int c = threadIdx.x;
        float sc = bn0g[c] * rsqrtf(bn0v[c] + BN_EPS);
        sSc[c] = sc;
        sSh[c] = bn0b[c] - bn0m[c] * sc;
    }
    __syncthreads();
    const int wid  = blockIdx.x * 4 + (threadIdx.x >> 6);
    const int lane = threadIdx.x & 63;
    const int c0 = lane * 2;
    float2 a = *(const float2*)(x2 + (size_t)wid * 128 + c0);
    float a0 = eluf(a.x * sSc[c0] + sSh[c0]);
    float a1 = eluf(a.y * sSc[c0 + 1] + sSh[c0 + 1]);
    float p[NCLS];
    #pragma unroll
    for (int j = 0; j < NCLS; ++j)
        p[j] = a0 * sW[c0 * 12 + j] + a1 * sW[(c0 + 1) * 12 + j];
    #pragma unroll
    for (int j = 0; j < NCLS; ++j) {
        float v = p[j];
        v += __shfl_xor(v, 1);  v += __shfl_xor(v, 2);  v += __shfl_xor(v, 4);
        v += __shfl_xor(v, 8);  v += __shfl_xor(v, 16); v += __shfl_xor(v, 32);
        p[j] = v;
    }
    float z[NCLS];
    #pragma unroll
    for (int j = 0; j < NCLS; ++j) z[j] = p[j] + outb[j];
    float m = z[0];
    #pragma unroll
    for (int j = 1; j < NCLS; ++j) m = fmaxf(m, z[j]);
    float ssum = 0.f;
    #pragma unroll
    for (int j = 0; j < NCLS; ++j) ssum += __expf(z[j] - m);
    float lse = m + __logf(ssum);
    #pragma unroll
    for (int j = 0; j < NCLS; ++j)
        if (lane == j) out[(size_t)wid * NCLS + j] = z[j] - lse;
}

// ---------------- launcher ----------------
extern "C" void kernel_launch(void* const* d_in, const int* in_sizes, int n_in,
                              void* d_out, int out_size, void* d_ws, size_t ws_size,
                              hipStream_t stream) {
    const float* x        = (const float*)d_in[0];
    const int*   edge_ix  = (const int*)  d_in[1];
    const int*   scat_idx = (const int*)  d_in[2];
    const float* scat_w   = (const float*)d_in[3];
    const float* lin_W    = (const float*)d_in[4];
    const float* lin_b    = (const float*)d_in[5];
    const float* gat_W    = (const float*)d_in[6];
    const float* att_src  = (const float*)d_in[7];
    const float* att_dst  = (const float*)d_in[8];
    const float* gat_b    = (const float*)d_in[9];
    const float* mlp_W    = (const float*)d_in[10];
    const float* mlp_b    = (const float*)d_in[11];
    const float* bn_g     = (const float*)d_in[12];
    const float* bn_b     = (const float*)d_in[13];
    const float* bn_m     = (const float*)d_in[14];
    const float* bn_v     = (const float*)d_in[15];
    const float* bn0_g    = (const float*)d_in[16];
    const float* bn0_b    = (const float*)d_in[17];
    const float* bn0_m    = (const float*)d_in[18];
    const float* bn0_v    = (const float*)d_in[19];
    const float* out_W    = (const float*)d_in[20];
    const float* out_b    = (const float*)d_in[21];
    float* out = (float*)d_out;

    char* ws = (char*)d_ws;
    unsigned short* xb    = (unsigned short*)(ws + OFF_U1);   // dead after LIN gemm
    unsigned short* xcur5 = (unsigned short*)(ws + OFF_U1);   // [5][N][128] after sp phase
    unsigned short* hb    = (unsigned short*)(ws + OFF_HB);
    float*          x2    = (float*)(ws + OFF_X2);
    unsigned short* hh    = (unsigned short*)(ws + OFF_HH);
    unsigned short* gout  = (unsigned short*)(ws + OFF_GOUT); // also tmp4 [4][N][128] pre-branch
    unsigned short* tmp4  = (unsigned short*)(ws + OFF_GOUT);
    unsigned short* wt    = (unsigned short*)(ws + OFF_WT);
    unsigned short* linWT = wt;                         // [128][512]
    unsigned short* gatWT = wt + 65536;                 // [5][512][128]
    unsigned short* mlpWT = wt + 65536 * 6;             // [5][128][512]
    int*   off6   = (int*)(ws + OFF_OFF6);
    int2*  spp    = (int2*)(ws + OFF_SPP);
    int*   g_src  = (int*)(ws + OFF_GSRC);
    int*   cnt6   = (int*)(ws + OFF_CNT);
    int*   cur6   = cnt6 + 6 * NN;
    float* asrc   = (float*)(ws + OFF_CNT);             // alias: CSR scratch dead after build
    float* adst   = asrc + (size_t)NN * 4;

    const dim3 b256(256);

    // ---- CSR build (all 6 graphs) ----
    hipMemsetAsync(cnt6, 0, (size_t)12 * NN * 4, stream);
    count_all<<<2048, b256, 0, stream>>>(scat_idx, edge_ix, cnt6);
    exscan30k<<<6, 1024, 0, stream>>>(cnt6, off6);
    fill_all<<<2048, b256, 0, stream>>>(scat_idx, scat_w, edge_ix, off6, cur6, spp, g_src);

    // ---- dtype conversions ----
    convx<<<2048, b256, 0, stream>>>(x, xb);
    transW<<<256, b256, 0, stream>>>(lin_W, linWT, 512, 128, 1);
    transW<<<640, b256, 0, stream>>>(gat_W, gatWT, 128, 512, 5);
    transW<<<640, b256, 0, stream>>>(mlp_W, mlpWT, 512, 128, 5);

    // ---- h = x @ lin_W + lin_b (bf16 out) ; x2 = h (f32) ----
    mgemm<512, 128, GM_LIN><<<dim3(469, 1), b256, 0, stream>>>(
        xb, linWT, lin_b, hb, x2, nullptr, nullptr, nullptr, nullptr, NN);

    // ---- batched solo passes: tmp (sets1-4, abs) then xcur[0..4] (set 0) ----
    sp_batch<0><<<dim3(7500, 4), b256, 0, stream>>>(off6, spp, hb, nullptr, tmp4);
    sp_batch<1><<<dim3(7500, 5), b256, 0, stream>>>(off6, spp, hb, tmp4, xcur5);

    // ---- 5 GAT branches ----
    for (int i = 0; i < NSETS; ++i) {
        mgemm<128, 512, GM_PLAIN><<<dim3(469, 4), b256, 0, stream>>>(
            xcur5 + (size_t)i * NN * 128, gatWT + (size_t)i * 65536, nullptr, hh, nullptr,
            nullptr, nullptr, nullptr, nullptr, NN);
        att_scores<<<7500, b256, 0, stream>>>(hh, att_src + (size_t)i * 512, att_dst + (size_t)i * 512,
                                              asrc, adst);
        gat_agg<<<7500, b256, 0, stream>>>(off6 + 5 * (NN + 1), g_src, asrc, adst,
                                           hh, gat_b + (size_t)i * 512, gout);
        mgemm<512, 128, GM_MLP><<<dim3(469, 1), b256, 0, stream>>>(
            gout, mlpWT + (size_t)i * 65536, mlp_b + (size_t)i * 128, nullptr, x2,
            bn_g + (size_t)i * 128, bn_b + (size_t)i * 128,
            bn_m + (size_t)i * 128, bn_v + (size_t)i * 128, NN);
    }

    // ---- final ----
    final_out<<<7500, b256, 0, stream>>>(x2, bn0_g, bn0_b, bn0_m, bn0_v, out_W, out_b, out);
}

// Round 4
// 1035.606 us; speedup vs baseline: 2.4025x; 1.2090x over previous
//
#include <hip/hip_runtime.h>
#include <cstdint>
#include <cstddef>

// ---------------- problem constants ----------------
#define NN 30000        // nodes
#define NE 400000       // edges per scatter set
#define EG (NE + NN)    // GAT edges incl self loops
#define NSETS 5
#define NCLS 10
#define BN_EPS 1e-5f

typedef __bf16 bf16x8 __attribute__((ext_vector_type(8)));
typedef float  f32x4  __attribute__((ext_vector_type(4)));

// ---------------- workspace layout (bytes) ----------------
// U1:   xb [N][512]bf16 (dead after LIN gemm) / xcur5 [5][N][128]bf16
// GOUT: gout [N][512]bf16  aliased with tmp4 [4][N][128]bf16 (tmp dead before gat_agg)
// CNT:  cnt6|cur6 ints (CSR build) aliased with as_/ad_ (used after build)
constexpr size_t alg(size_t x) { return (x + 255) & ~size_t(255); }
constexpr size_t OFF_U1    = 0;
constexpr size_t OFF_HB    = OFF_U1   + alg((size_t)5 * NN * 128 * 2);
constexpr size_t OFF_X2    = OFF_HB   + alg((size_t)NN * 128 * 2);
constexpr size_t OFF_HH    = OFF_X2   + alg((size_t)NN * 128 * 4);
constexpr size_t OFF_GOUT  = OFF_HH   + alg((size_t)NN * 512 * 2);
constexpr size_t OFF_WT    = OFF_GOUT + alg((size_t)NN * 512 * 2);
constexpr size_t OFF_OFF6  = OFF_WT   + alg((size_t)11 * 65536 * 2);
constexpr size_t OFF_SPP   = OFF_OFF6 + alg((size_t)6 * (NN + 1) * 4);
constexpr size_t OFF_GSRC  = OFF_SPP  + alg((size_t)NSETS * NE * 8);
constexpr size_t OFF_CNT   = OFF_GSRC + alg((size_t)EG * 4);
constexpr size_t WS_NEED   = OFF_CNT  + alg((size_t)12 * NN * 4);   // ~144.2 MB

// ---------------- helpers ----------------
__device__ __forceinline__ float lrelu02(float v) { return v > 0.f ? v : 0.2f * v; }
__device__ __forceinline__ float eluf(float v)    { return v > 0.f ? v : __expf(v) - 1.f; }
__device__ __forceinline__ float bf2f(unsigned u) {
    union { unsigned i; float f; } c; c.i = u << 16; return c.f;
}
__device__ __forceinline__ unsigned short f2bf(float f) {
    union { float f; unsigned i; } c; c.f = f;
    unsigned u = c.i + 0x7FFFu + ((c.i >> 16) & 1u);
    return (unsigned short)(u >> 16);
}
__device__ __forceinline__ void gload_lds16(const void* g, void* l) {
    __builtin_amdgcn_global_load_lds(
        (const __attribute__((address_space(1))) void*)(uintptr_t)g,
        (__attribute__((address_space(3))) void*)(unsigned)(uintptr_t)l,
        16, 0, 0);
}

// ---------------- CSR build (fused over 5 sets + GAT graph) ----------------
__global__ void count_all(const int* __restrict__ scat_idx, const int* __restrict__ edge_ix,
                          int* __restrict__ cnt6) {
    const int total = NSETS * NE + EG;
    for (int i = blockIdx.x * blockDim.x + threadIdx.x; i < total; i += gridDim.x * blockDim.x) {
        if (i < NSETS * NE) {
            int s = i / NE, e = i - s * NE;
            atomicAdd(&cnt6[s * NN + scat_idx[(size_t)s * 2 * NE + NE + e]], 1);
        } else {
            int j = i - NSETS * NE;
            int d = (j < NE) ? edge_ix[NE + j] : (j - NE);
            atomicAdd(&cnt6[5 * NN + d], 1);
        }
    }
}

__global__ void exscan30k(const int* __restrict__ cnt6, int* __restrict__ off6) {
    const int* cnt = cnt6 + blockIdx.x * NN;
    int* off = off6 + blockIdx.x * (NN + 1);
    constexpr int per = 30;
    __shared__ int s[1024];
    const int t = threadIdx.x;
    const int base0 = t * per;
    int sum = 0;
    #pragma unroll
    for (int i = 0; i < per; ++i) { int idx = base0 + i; sum += (idx < NN) ? cnt[idx] : 0; }
    s[t] = sum;
    __syncthreads();
    for (int d = 1; d < 1024; d <<= 1) {
        int v = (t >= d) ? s[t - d] : 0;
        __syncthreads();
        s[t] += v;
        __syncthreads();
    }
    int run = s[t] - sum;
    #pragma unroll
    for (int i = 0; i < per; ++i) {
        int idx = base0 + i;
        if (idx < NN) { off[idx] = run; run += cnt[idx]; }
    }
    if (t == 1023) off[NN] = s[1023];
}

__global__ void fill_all(const int* __restrict__ scat_idx, const float* __restrict__ scat_w,
                         const int* __restrict__ edge_ix, const int* __restrict__ off6,
                         int* __restrict__ cur6, int2* __restrict__ spp,
                         int* __restrict__ g_src) {
    const int total = NSETS * NE + EG;
    for (int i = blockIdx.x * blockDim.x + threadIdx.x; i < total; i += gridDim.x * blockDim.x) {
        if (i < NSETS * NE) {
            int s = i / NE, e = i - s * NE;
            int d = scat_idx[(size_t)s * 2 * NE + NE + e];
            int p = off6[s * (NN + 1) + d] + atomicAdd(&cur6[s * NN + d], 1);
            int2 pk;
            pk.x = scat_idx[(size_t)s * 2 * NE + e];
            pk.y = __float_as_int(scat_w[(size_t)s * NE + e]);
            spp[(size_t)s * NE + p] = pk;
        } else {
            int j = i - NSETS * NE;
            int sidx, d;
            if (j < NE) { sidx = edge_ix[j]; d = edge_ix[NE + j]; }
            else        { sidx = j - NE;     d = sidx; }
            int p = off6[5 * (NN + 1) + d] + atomicAdd(&cur6[5 * NN + d], 1);
            g_src[p] = sidx;
        }
    }
}

// ---------------- conversions ----------------
__global__ void convx(const float* __restrict__ x, unsigned short* __restrict__ xb) {
    const int total = NN * 512 / 4;
    for (int i = blockIdx.x * blockDim.x + threadIdx.x; i < total; i += gridDim.x * blockDim.x) {
        float4 v = *(const float4*)(x + (size_t)i * 4);
        ushort4 o;
        o.x = f2bf(v.x); o.y = f2bf(v.y); o.z = f2bf(v.z); o.w = f2bf(v.w);
        *(ushort4*)(xb + (size_t)i * 4) = o;
    }
}

// W [B][K][N] f32 -> WT [B][N][K] bf16
__global__ void transW(const float* __restrict__ W, unsigned short* __restrict__ WT,
                       int Kd, int Nd, int B) {
    const int total = B * Kd * Nd;
    for (int i = blockIdx.x * blockDim.x + threadIdx.x; i < total; i += gridDim.x * blockDim.x) {
        int b = i / (Kd * Nd);
        int r = i - b * Kd * Nd;
        int n = r / Kd, k = r - n * Kd;
        WT[i] = f2bf(W[(size_t)b * Kd * Nd + (size_t)k * Nd + n]);
    }
}

// ---------------- MFMA bf16 GEMM: C[M][NC] = A[M][K] @ BT[NC][K]^T ----------------
template<int ROWS>
__device__ __forceinline__ void stage64(const unsigned short* __restrict__ src, int ld,
                                        int row0, int maxrow, int k0, char* lds, int t) {
    const int wave = t >> 6, lane = t & 63;
    const int sub = lane >> 3;
    const int kch = (lane & 7) ^ sub;
    for (int j = wave; j < ROWS / 8; j += 4) {
        int grow = row0 + j * 8 + sub;
        if (grow > maxrow) grow = maxrow;
        gload_lds16(src + (size_t)grow * ld + k0 + kch * 8, lds + j * 1024);
    }
}

#define GM_LIN 0
#define GM_PLAIN 1
#define GM_MLP 2

template<int K, int NC, int MODE>
__global__ void __launch_bounds__(256) mgemm(const unsigned short* __restrict__ A,
                                             const unsigned short* __restrict__ BT,
                                             const float* __restrict__ bias,
                                             unsigned short* __restrict__ outb,
                                             float* __restrict__ x2,
                                             const float* __restrict__ bng, const float* __restrict__ bnb,
                                             const float* __restrict__ bnm, const float* __restrict__ bnv,
                                             int M) {
    __shared__ __align__(16) char As[64 * 128];
    __shared__ __align__(16) char Bs[128 * 128];
    const int t = threadIdx.x, wave = t >> 6, lane = t & 63;
    const int bm = blockIdx.x * 64, bn = blockIdx.y * 128;
    const int wr = (wave >> 1) * 32, wc = (wave & 1) * 64;
    const int l15 = lane & 15, l4 = lane >> 4;
    const int rsw = (l15 & 7) << 4;
    f32x4 acc[2][4] = {};

    for (int kt = 0; kt < K; kt += 64) {
        stage64<64>(A, K, bm, M - 1, kt, As, t);
        stage64<128>(BT, K, bn, NC - 1, kt, Bs, t);
        __syncthreads();
        #pragma unroll
        for (int kk = 0; kk < 2; ++kk) {
            bf16x8 af[2], bf[4];
            const int koff = kk * 64 + l4 * 16;
            #pragma unroll
            for (int fm = 0; fm < 2; ++fm) {
                int r = wr + fm * 16 + l15;
                af[fm] = *(const bf16x8*)(As + r * 128 + (koff ^ rsw));
            }
            #pragma unroll
            for (int fn = 0; fn < 4; ++fn) {
                int c = wc + fn * 16 + l15;
                bf[fn] = *(const bf16x8*)(Bs + c * 128 + (koff ^ rsw));
            }
            #pragma unroll
            for (int fm = 0; fm < 2; ++fm)
                #pragma unroll
                for (int fn = 0; fn < 4; ++fn)
                    acc[fm][fn] = __builtin_amdgcn_mfma_f32_16x16x32_bf16(af[fm], bf[fn], acc[fm][fn], 0, 0, 0);
        }
        __syncthreads();
    }

    #pragma unroll
    for (int fn = 0; fn < 4; ++fn) {
        const int c = bn + wc + fn * 16 + l15;
        float bias_c = 0.f, sc = 0.f, sh = 0.f;
        if constexpr (MODE == GM_LIN) bias_c = bias[c];
        if constexpr (MODE == GM_MLP) {
            bias_c = bias[c];
            sc = bng[c] * rsqrtf(bnv[c] + BN_EPS);
            sh = bnb[c] - bnm[c] * sc;
        }
        #pragma unroll
        for (int fm = 0; fm < 2; ++fm) {
            #pragma unroll
            for (int rg = 0; rg < 4; ++rg) {
                int r = bm + wr + fm * 16 + l4 * 4 + rg;
                if (r < M) {
                    float v = acc[fm][fn][rg];
                    if constexpr (MODE == GM_LIN) {
                        v += bias_c;
                        outb[(size_t)r * NC + c] = f2bf(v);
                        x2[(size_t)r * NC + c] = v;
                    } else if constexpr (MODE == GM_PLAIN) {
                        outb[(size_t)r * NC + c] = f2bf(v);
                    } else {
                        x2[(size_t)r * NC + c] += (v + bias_c) * sc + sh;
                    }
                }
            }
        }
    }
}

// ---------------- phase 0: tmp_y = abs(sp(y+1, hb)), 4-way edge unroll ----------------
__global__ void __launch_bounds__(256) sp_abs4(const int* __restrict__ off6,
                                               const int2* __restrict__ spp,
                                               const unsigned short* __restrict__ hb,
                                               unsigned short* __restrict__ tmp4) {
    const int y = blockIdx.y;
    const int* off = off6 + (y + 1) * (NN + 1);
    const int2* pk = spp + (size_t)(y + 1) * NE;
    unsigned short* out = tmp4 + (size_t)y * NN * 128;

    const int wid  = blockIdx.x * 4 + (threadIdx.x >> 6);
    const int lane = threadIdx.x & 63;
    const int co   = lane * 2;
    const int s0 = off[wid], s1 = off[wid + 1];
    float a0 = 0.f, a1 = 0.f;
    int j = s0;
    for (; j + 3 < s1; j += 4) {
        int2 e0 = pk[j], e1 = pk[j + 1], e2 = pk[j + 2], e3 = pk[j + 3];
        unsigned v0 = *(const unsigned*)(hb + (size_t)e0.x * 128 + co);
        unsigned v1 = *(const unsigned*)(hb + (size_t)e1.x * 128 + co);
        unsigned v2 = *(const unsigned*)(hb + (size_t)e2.x * 128 + co);
        unsigned v3 = *(const unsigned*)(hb + (size_t)e3.x * 128 + co);
        float w0 = __int_as_float(e0.y), w1 = __int_as_float(e1.y);
        float w2 = __int_as_float(e2.y), w3 = __int_as_float(e3.y);
        a0 = fmaf(w0, bf2f(v0 & 0xffffu), a0); a1 = fmaf(w0, bf2f(v0 >> 16), a1);
        a0 = fmaf(w1, bf2f(v1 & 0xffffu), a0); a1 = fmaf(w1, bf2f(v1 >> 16), a1);
        a0 = fmaf(w2, bf2f(v2 & 0xffffu), a0); a1 = fmaf(w2, bf2f(v2 >> 16), a1);
        a0 = fmaf(w3, bf2f(v3 & 0xffffu), a0); a1 = fmaf(w3, bf2f(v3 >> 16), a1);
    }
    for (; j < s1; ++j) {
        int2 e = pk[j];
        float wj = __int_as_float(e.y);
        unsigned v = *(const unsigned*)(hb + (size_t)e.x * 128 + co);
        a0 = fmaf(wj, bf2f(v & 0xffffu), a0);
        a1 = fmaf(wj, bf2f(v >> 16), a1);
    }
    a0 = fabsf(a0); a1 = fabsf(a1);
    unsigned o = (unsigned)f2bf(a0) | ((unsigned)f2bf(a1) << 16);
    *(unsigned*)(out + (size_t)wid * 128 + co) = o;
}

// ---------------- phase 1: xcur_y = sp(0, {hb,tmp0..3}), all 5 fused, 2-way unroll ----------------
__global__ void __launch_bounds__(256) sp_fused5(const int* __restrict__ off0,
                                                 const int2* __restrict__ spp0,
                                                 const unsigned short* __restrict__ hb,
                                                 const unsigned short* __restrict__ tmp4,
                                                 unsigned short* __restrict__ xcur5) {
    const int wid  = blockIdx.x * 4 + (threadIdx.x >> 6);
    const int lane = threadIdx.x & 63;
    const int co   = lane * 2;
    const int s0 = off0[wid], s1 = off0[wid + 1];
    const unsigned short* t0 = tmp4;
    const unsigned short* t1 = tmp4 + (size_t)1 * NN * 128;
    const unsigned short* t2 = tmp4 + (size_t)2 * NN * 128;
    const unsigned short* t3 = tmp4 + (size_t)3 * NN * 128;

    float a[5][2] = {};
    int j = s0;
    for (; j + 1 < s1; j += 2) {
        int2 eA = spp0[j], eB = spp0[j + 1];
        size_t rA = (size_t)eA.x * 128 + co, rB = (size_t)eB.x * 128 + co;
        unsigned vA0 = *(const unsigned*)(hb + rA), vB0 = *(const unsigned*)(hb + rB);
        unsigned vA1 = *(const unsigned*)(t0 + rA), vB1 = *(const unsigned*)(t0 + rB);
        unsigned vA2 = *(const unsigned*)(t1 + rA), vB2 = *(const unsigned*)(t1 + rB);
        unsigned vA3 = *(const unsigned*)(t2 + rA), vB3 = *(const unsigned*)(t2 + rB);
        unsigned vA4 = *(const unsigned*)(t3 + rA), vB4 = *(const unsigned*)(t3 + rB);
        float wA = __int_as_float(eA.y), wB = __int_as_float(eB.y);
        a[0][0] = fmaf(wA, bf2f(vA0 & 0xffffu), a[0][0]); a[0][1] = fmaf(wA, bf2f(vA0 >> 16), a[0][1]);
        a[1][0] = fmaf(wA, bf2f(vA1 & 0xffffu), a[1][0]); a[1][1] = fmaf(wA, bf2f(vA1 >> 16), a[1][1]);
        a[2][0] = fmaf(wA, bf2f(vA2 & 0xffffu), a[2][0]); a[2][1] = fmaf(wA, bf2f(vA2 >> 16), a[2][1]);
        a[3][0] = fmaf(wA, bf2f(vA3 & 0xffffu), a[3][0]); a[3][1] = fmaf(wA, bf2f(vA3 >> 16), a[3][1]);
        a[4][0] = fmaf(wA, bf2f(vA4 & 0xffffu), a[4][0]); a[4][1] = fmaf(wA, bf2f(vA4 >> 16), a[4][1]);
        a[0][0] = fmaf(wB, bf2f(vB0 & 0xffffu), a[0][0]); a[0][1] = fmaf(wB, bf2f(vB0 >> 16), a[0][1]);
        a[1][0] = fmaf(wB, bf2f(vB1 & 0xffffu), a[1][0]); a[1][1] = fmaf(wB, bf2f(vB1 >> 16), a[1][1]);
        a[2][0] = fmaf(wB, bf2f(vB2 & 0xffffu), a[2][0]); a[2][1] = fmaf(wB, bf2f(vB2 >> 16), a[2][1]);
        a[3][0] = fmaf(wB, bf2f(vB3 & 0xffffu), a[3][0]); a[3][1] = fmaf(wB, bf2f(vB3 >> 16), a[3][1]);
        a[4][0] = fmaf(wB, bf2f(vB4 & 0xffffu), a[4][0]); a[4][1] = fmaf(wB, bf2f(vB4 >> 16), a[4][1]);
    }
    if (j < s1) {
        int2 e = spp0[j];
        size_t r = (size_t)e.x * 128 + co;
        unsigned v0 = *(const unsigned*)(hb + r);
        unsigned v1 = *(const unsigned*)(t0 + r);
        unsigned v2 = *(const unsigned*)(t1 + r);
        unsigned v3 = *(const unsigned*)(t2 + r);
        unsigned v4 = *(const unsigned*)(t3 + r);
        float wj = __int_as_float(e.y);
        a[0][0] = fmaf(wj, bf2f(v0 & 0xffffu), a[0][0]); a[0][1] = fmaf(wj, bf2f(v0 >> 16), a[0][1]);
        a[1][0] = fmaf(wj, bf2f(v1 & 0xffffu), a[1][0]); a[1][1] = fmaf(wj, bf2f(v1 >> 16), a[1][1]);
        a[2][0] = fmaf(wj, bf2f(v2 & 0xffffu), a[2][0]); a[2][1] = fmaf(wj, bf2f(v2 >> 16), a[2][1]);
        a[3][0] = fmaf(wj, bf2f(v3 & 0xffffu), a[3][0]); a[3][1] = fmaf(wj, bf2f(v3 >> 16), a[3][1]);
        a[4][0] = fmaf(wj, bf2f(v4 & 0xffffu), a[4][0]); a[4][1] = fmaf(wj, bf2f(v4 >> 16), a[4][1]);
    }
    #pragma unroll
    for (int y = 0; y < 5; ++y) {
        unsigned o = (unsigned)f2bf(a[y][0]) | ((unsigned)f2bf(a[y][1]) << 16);
        *(unsigned*)(xcur5 + (size_t)y * NN * 128 + (size_t)wid * 128 + co) = o;
    }
}

// ---------------- GAT attention scores ----------------
__global__ void __launch_bounds__(256) att_scores(const unsigned short* __restrict__ hh,
                                                  const float* __restrict__ att_s, const float* __restrict__ att_d,
                                                  float* __restrict__ as_, float* __restrict__ ad_) {
    __shared__ float ss[512], sd[512];
    for (int i = threadIdx.x; i < 512; i += 256) { ss[i] = att_s[i]; sd[i] = att_d[i]; }
    __syncthreads();
    const int wid  = blockIdx.x * 4 + (threadIdx.x >> 6);
    const int lane = threadIdx.x & 63;
    uint4 v = *(const uint4*)(hh + (size_t)wid * 512 + lane * 8);
    float f[8];
    f[0] = bf2f(v.x & 0xffffu); f[1] = bf2f(v.x >> 16);
    f[2] = bf2f(v.y & 0xffffu); f[3] = bf2f(v.y >> 16);
    f[4] = bf2f(v.z & 0xffffu); f[5] = bf2f(v.z >> 16);
    f[6] = bf2f(v.w & 0xffffu); f[7] = bf2f(v.w >> 16);
    float ps = 0.f, pd = 0.f;
    #pragma unroll
    for (int c = 0; c < 8; ++c) {
        ps = fmaf(f[c], ss[lane * 8 + c], ps);
        pd = fmaf(f[c], sd[lane * 8 + c], pd);
    }
    #pragma unroll
    for (int d = 1; d < 16; d <<= 1) { ps += __shfl_xor(ps, d); pd += __shfl_xor(pd, d); }
    if ((lane & 15) == 0) {
        const int hd = lane >> 4;
        as_[(size_t)wid * 4 + hd] = ps;
        ad_[(size_t)wid * 4 + hd] = pd;
    }
}

// ---------------- GAT aggregation (fused online softmax) + bias + ELU -> bf16 gout ----------------
__device__ __forceinline__ void acc8(float* a, float al, uint4 v) {
    a[0] = fmaf(al, bf2f(v.x & 0xffffu), a[0]); a[1] = fmaf(al, bf2f(v.x >> 16), a[1]);
    a[2] = fmaf(al, bf2f(v.y & 0xffffu), a[2]); a[3] = fmaf(al, bf2f(v.y >> 16), a[3]);
    a[4] = fmaf(al, bf2f(v.z & 0xffffu), a[4]); a[5] = fmaf(al, bf2f(v.z >> 16), a[5]);
    a[6] = fmaf(al, bf2f(v.w & 0xffffu), a[6]); a[7] = fmaf(al, bf2f(v.w >> 16), a[7]);
}

__global__ void __launch_bounds__(256) gat_agg(const int* __restrict__ goff, const int* __restrict__ gsrc,
                                               const float* __restrict__ as_, const float* __restrict__ ad_,
                                               const unsigned short* __restrict__ hh,
                                               const float* __restrict__ gat_b,
                                               unsigned short* __restrict__ gout) {
    const int wid  = blockIdx.x * 4 + (threadIdx.x >> 6);
    const int lane = threadIdx.x & 63;
    const int s0 = goff[wid], s1 = goff[wid + 1];
    const float4 adv4 = *(const float4*)(ad_ + (size_t)wid * 4);

    // phase 1: online max + exp-sum per head, all 64 lanes over edge subsets
    float m[4] = {-1e30f, -1e30f, -1e30f, -1e30f};
    float s[4] = {0.f, 0.f, 0.f, 0.f};
    for (int j = s0 + lane; j < s1; j += 64) {
        const int si = gsrc[j];
        float4 av = *(const float4*)(as_ + (size_t)si * 4);
        float e[4] = {lrelu02(av.x + adv4.x), lrelu02(av.y + adv4.y),
                      lrelu02(av.z + adv4.z), lrelu02(av.w + adv4.w)};
        #pragma unroll
        for (int h = 0; h < 4; ++h) {
            if (e[h] > m[h]) { s[h] = s[h] * __expf(m[h] - e[h]) + 1.f; m[h] = e[h]; }
            else             { s[h] += __expf(e[h] - m[h]); }
        }
    }
    #pragma unroll
    for (int d = 1; d < 64; d <<= 1) {
        #pragma unroll
        for (int h = 0; h < 4; ++h) {
            float om = __shfl_xor(m[h], d);
            float os = __shfl_xor(s[h], d);
            float nm = fmaxf(m[h], om);
            s[h] = s[h] * __expf(m[h] - nm) + os * __expf(om - nm);
            m[h] = nm;
        }
    }
    const int hd = lane >> 4;
    const float advh = hd == 0 ? adv4.x : hd == 1 ? adv4.y : hd == 2 ? adv4.z : adv4.w;
    const float mv   = hd == 0 ? m[0]   : hd == 1 ? m[1]   : hd == 2 ? m[2]   : m[3];
    const float dv   = hd == 0 ? s[0]   : hd == 1 ? s[1]   : hd == 2 ? s[2]   : s[3];
    const float inv  = 1.f / (dv + 1e-16f);

    // phase 2: channel accumulation, 4-way edge unroll
    float a[8] = {};
    int j = s0;
    for (; j + 3 < s1; j += 4) {
        int i0 = gsrc[j], i1 = gsrc[j + 1], i2 = gsrc[j + 2], i3 = gsrc[j + 3];
        float q0 = as_[(size_t)i0 * 4 + hd], q1 = as_[(size_t)i1 * 4 + hd];
        float q2 = as_[(size_t)i2 * 4 + hd], q3 = as_[(size_t)i3 * 4 + hd];
        uint4 v0 = *(const uint4*)(hh + (size_t)i0 * 512 + lane * 8);
        uint4 v1 = *(const uint4*)(hh + (size_t)i1 * 512 + lane * 8);
        uint4 v2 = *(const uint4*)(hh + (size_t)i2 * 512 + lane * 8);
        uint4 v3 = *(const uint4*)(hh + (size_t)i3 * 512 + lane * 8);
        float al0 = __expf(lrelu02(q0 + advh) - mv) * inv;
        float al1 = __expf(lrelu02(q1 + advh) - mv) * inv;
        float al2 = __expf(lrelu02(q2 + advh) - mv) * inv;
        float al3 = __expf(lrelu02(q3 + advh) - mv) * inv;
        acc8(a, al0, v0); acc8(a, al1, v1); acc8(a, al2, v2); acc8(a, al3, v3);
    }
    for (; j < s1; ++j) {
        int si = gsrc[j];
        float e = lrelu02(as_[(size_t)si * 4 + hd] + advh);
        float alpha = __expf(e - mv) * inv;
        uint4 v = *(const uint4*)(hh + (size_t)si * 512 + lane * 8);
        acc8(a, alpha, v);
    }
    unsigned short o[8];
    #pragma unroll
    for (int c = 0; c < 8; ++c)
        o[c] = f2bf(eluf(a[c] + gat_b[lane * 8 + c]));
    uint4 ov;
    ov.x = (unsigned)o[0] | ((unsigned)o[1] << 16);
    ov.y = (unsigned)o[2] | ((unsigned)o[3] << 16);
    ov.z = (unsigned)o[4] | ((unsigned)o[5] << 16);
    ov.w = (unsigned)o[6] | ((unsigned)o[7] << 16);
    *(uint4*)(gout + (size_t)wid * 512 + lane * 8) = ov;
}

// ---------------- final: out = log_softmax( elu(bn0(x2)) @ outW + outb ) ----------------
__global__ void __launch_bounds__(256) final_out(const float* __restrict__ x2,
                                                 const float* __restrict__ bn0g, const float* __restrict__ bn0b,
                                                 const float* __restrict__ bn0m, const float* __restrict__ bn0v,
                                                 const float* __restrict__ outW, const float* __restrict__ outb,
                                                 float* __restrict__ out) {
    __shared__ float sW[128 * 12];
    __shared__ float sSc[128], sSh[128];
    for (int i = threadIdx.x; i < 1280; i += 256) {
        int r = i / 10, c = i - r * 10;
        sW[r * 12 + c] = outW[i];
    }
    if (threadIdx.x < 128) {
        int c = threadIdx.x;
        float sc = bn0g[c] * rsqrtf(bn0v[c] + BN_EPS);
        sSc[c] = sc;
        sSh[c] = bn0b[c] - bn0m[c] * sc;
    }
    __syncthreads();
    const int wid  = blockIdx.x * 4 + (threadIdx.x >> 6);
    const int lane = threadIdx.x & 63;
    const int c0 = lane * 2;
    float2 a = *(const float2*)(x2 + (size_t)wid * 128 + c0);
    float a0 = eluf(a.x * sSc[c0] + sSh[c0]);
    float a1 = eluf(a.y * sSc[c0 + 1] + sSh[c0 + 1]);
    float p[NCLS];
    #pragma unroll
    for (int j = 0; j < NCLS; ++j)
        p[j] = a0 * sW[c0 * 12 + j] + a1 * sW[(c0 + 1) * 12 + j];
    #pragma unroll
    for (int j = 0; j < NCLS; ++j) {
        float v = p[j];
        v += __shfl_xor(v, 1);  v += __shfl_xor(v, 2);  v += __shfl_xor(v, 4);
        v += __shfl_xor(v, 8);  v += __shfl_xor(v, 16); v += __shfl_xor(v, 32);
        p[j] = v;
    }
    float z[NCLS];
    #pragma unroll
    for (int j = 0; j < NCLS; ++j) z[j] = p[j] + outb[j];
    float m = z[0];
    #pragma unroll
    for (int j = 1; j < NCLS; ++j) m = fmaxf(m, z[j]);
    float ssum = 0.f;
    #pragma unroll
    for (int j = 0; j < NCLS; ++j) ssum += __expf(z[j] - m);
    float lse = m + __logf(ssum);
    #pragma unroll
    for (int j = 0; j < NCLS; ++j)
        if (lane == j) out[(size_t)wid * NCLS + j] = z[j] - lse;
}

// ---------------- launcher ----------------
extern "C" void kernel_launch(void* const* d_in, const int* in_sizes, int n_in,
                              void* d_out, int out_size, void* d_ws, size_t ws_size,
                              hipStream_t stream) {
    const float* x        = (const float*)d_in[0];
    const int*   edge_ix  = (const int*)  d_in[1];
    const int*   scat_idx = (const int*)  d_in[2];
    const float* scat_w   = (const float*)d_in[3];
    const float* lin_W    = (const float*)d_in[4];
    const float* lin_b    = (const float*)d_in[5];
    const float* gat_W    = (const float*)d_in[6];
    const float* att_src  = (const float*)d_in[7];
    const float* att_dst  = (const float*)d_in[8];
    const float* gat_b    = (const float*)d_in[9];
    const float* mlp_W    = (const float*)d_in[10];
    const float* mlp_b    = (const float*)d_in[11];
    const float* bn_g     = (const float*)d_in[12];
    const float* bn_b     = (const float*)d_in[13];
    const float* bn_m     = (const float*)d_in[14];
    const float* bn_v     = (const float*)d_in[15];
    const float* bn0_g    = (const float*)d_in[16];
    const float* bn0_b    = (const float*)d_in[17];
    const float* bn0_m    = (const float*)d_in[18];
    const float* bn0_v    = (const float*)d_in[19];
    const float* out_W    = (const float*)d_in[20];
    const float* out_b    = (const float*)d_in[21];
    float* out = (float*)d_out;

    char* ws = (char*)d_ws;
    unsigned short* xb    = (unsigned short*)(ws + OFF_U1);
    unsigned short* xcur5 = (unsigned short*)(ws + OFF_U1);
    unsigned short* hb    = (unsigned short*)(ws + OFF_HB);
    float*          x2    = (float*)(ws + OFF_X2);
    unsigned short* hh    = (unsigned short*)(ws + OFF_HH);
    unsigned short* gout  = (unsigned short*)(ws + OFF_GOUT);
    unsigned short* tmp4  = (unsigned short*)(ws + OFF_GOUT);
    unsigned short* wt    = (unsigned short*)(ws + OFF_WT);
    unsigned short* linWT = wt;
    unsigned short* gatWT = wt + 65536;
    unsigned short* mlpWT = wt + 65536 * 6;
    int*   off6   = (int*)(ws + OFF_OFF6);
    int2*  spp    = (int2*)(ws + OFF_SPP);
    int*   g_src  = (int*)(ws + OFF_GSRC);
    int*   cnt6   = (int*)(ws + OFF_CNT);
    int*   cur6   = cnt6 + 6 * NN;
    float* asrc   = (float*)(ws + OFF_CNT);
    float* adst   = asrc + (size_t)NN * 4;

    const dim3 b256(256);

    // ---- CSR build (all 6 graphs) ----
    hipMemsetAsync(cnt6, 0, (size_t)12 * NN * 4, stream);
    count_all<<<2048, b256, 0, stream>>>(scat_idx, edge_ix, cnt6);
    exscan30k<<<6, 1024, 0, stream>>>(cnt6, off6);
    fill_all<<<2048, b256, 0, stream>>>(scat_idx, scat_w, edge_ix, off6, cur6, spp, g_src);

    // ---- dtype conversions ----
    convx<<<2048, b256, 0, stream>>>(x, xb);
    transW<<<256, b256, 0, stream>>>(lin_W, linWT, 512, 128, 1);
    transW<<<640, b256, 0, stream>>>(gat_W, gatWT, 128, 512, 5);
    transW<<<640, b256, 0, stream>>>(mlp_W, mlpWT, 512, 128, 5);

    // ---- h = x @ lin_W + lin_b (bf16 out) ; x2 = h (f32) ----
    mgemm<512, 128, GM_LIN><<<dim3(469, 1), b256, 0, stream>>>(
        xb, linWT, lin_b, hb, x2, nullptr, nullptr, nullptr, nullptr, NN);

    // ---- solo passes ----
    sp_abs4<<<dim3(7500, 4), b256, 0, stream>>>(off6, spp, hb, tmp4);
    sp_fused5<<<7500, b256, 0, stream>>>(off6, spp, hb, tmp4, xcur5);

    // ---- 5 GAT branches ----
    for (int i = 0; i < NSETS; ++i) {
        mgemm<128, 512, GM_PLAIN><<<dim3(469, 4), b256, 0, stream>>>(
            xcur5 + (size_t)i * NN * 128, gatWT + (size_t)i * 65536, nullptr, hh, nullptr,
            nullptr, nullptr, nullptr, nullptr, NN);
        att_scores<<<7500, b256, 0, stream>>>(hh, att_src + (size_t)i * 512, att_dst + (size_t)i * 512,
                                              asrc, adst);
        gat_agg<<<7500, b256, 0, stream>>>(off6 + 5 * (NN + 1), g_src, asrc, adst,
                                           hh, gat_b + (size_t)i * 512, gout);
        mgemm<512, 128, GM_MLP><<<dim3(469, 1), b256, 0, stream>>>(
            gout, mlpWT + (size_t)i * 65536, mlp_b + (size_t)i * 128, nullptr, x2,
            bn_g + (size_t)i * 128, bn_b + (size_t)i * 128,
            bn_m + (size_t)i * 128, bn_v + (size_t)i * 128, NN);
    }

    // ---- final ----
    final_out<<<7500, b256, 0, stream>>>(x2, bn0_g, bn0_b, bn0_m, bn0_v, out_W, out_b, out);
}